// Round 2
// baseline (1726.425 us; speedup 1.0000x reference)
//
#include <hip/hip_runtime.h>
#include <stdint.h>

#define NB 8
#define NPTS 4096
#define NS 1024
#define NK 32
#define NROWS (NB*NS*NK)   // 262144
#define R2 0.04f
#define NCOPY 32           // atomic spreading copies for stats accum

typedef __attribute__((ext_vector_type(8))) short bf16x8;   // 8 bf16 in 4 VGPRs
typedef __attribute__((ext_vector_type(4))) float f32x4;    // MFMA 16x16 accumulator
typedef __attribute__((ext_vector_type(2))) float f32x2;    // packed fp32 (v_pk_*)

__device__ __forceinline__ float bf2f(uint16_t u){
    uint32_t v = ((uint32_t)u) << 16;
    return __uint_as_float(v);
}
__device__ __forceinline__ uint16_t f2bf(float f){
    uint32_t u = __float_as_uint(f);
    uint32_t r = (u + 0x7FFFu + ((u >> 16) & 1u)) >> 16;
    return (uint16_t)r;
}
__device__ __forceinline__ bf16x8 load_bf8(const uint16_t* p){
    return *reinterpret_cast<const bf16x8*>(p);
}

// LDS-only barrier: waits ds ops (cand exchange) but does NOT drain outstanding
// global stores (the per-iteration publish). __syncthreads() would emit
// s_waitcnt vmcnt(0) before s_barrier, putting the publish store's coherence-
// point ack latency on the fps serial critical path every iteration.
#define BAR_LGKM() asm volatile("s_waitcnt lgkmcnt(0)\n\ts_barrier" ::: "memory")

// ---------------------------------------------------------------- producer/consumer plumbing
// Centroid publish: ONE 16B L2-bypass store {x,y,z,flag=1.0f}. sc0+sc1 makes the
// store visible at the coherent point past the non-coherent per-XCD L2s.
// Flag travels in the same 16B transaction as the coords -> no vmcnt wait, no
// release fence needed on the (latency-critical) fps wave.
__device__ __forceinline__ void publish_cent(float* cent, int cell,
                                             float cx, float cy, float cz){
    f32x4 v; v[0] = cx; v[1] = cy; v[2] = cz; v[3] = 1.0f;
    unsigned long long a = (unsigned long long)(uintptr_t)(cent + (size_t)cell*4);
    asm volatile("global_store_dwordx4 %0, %1, off sc0 sc1"
                 :: "v"(a), "v"(v) : "memory");
}
// Consumer: poll the flag word with an agent-scope relaxed load (bypasses stale
// L2), s_sleep between polls; once set, re-read the full 16B with a bypass load.
__device__ __forceinline__ f32x4 wait_cent(const float* cent, int cell){
    const uint32_t* wp = (const uint32_t*)(cent + (size_t)cell*4) + 3;
    while (__hip_atomic_load(wp, __ATOMIC_RELAXED, __HIP_MEMORY_SCOPE_AGENT)
           != 0x3F800000u)
        __builtin_amdgcn_s_sleep(32);
    f32x4 r;
    unsigned long long a = (unsigned long long)(uintptr_t)(cent + (size_t)cell*4);
    asm volatile("global_load_dwordx4 %0, %1, off sc0 sc1\n\ts_waitcnt vmcnt(0)"
                 : "=v"(r) : "v"(a) : "memory");
    return r;
}

// ---------------------------------------------------------------- last-block BN-param fold
// The 4096th block to finish stats computes {scale, shift} once (bit-identical
// double math, same cp summation order as the old per-block preambles).
__device__ __forceinline__ void compute_scsh(const double* accum, const float* g,
                                             const float* be, int nch,
                                             float* scsh, int t){
    if (t < nch){
        double s = 0.0, qq = 0.0;
#pragma unroll
        for (int cp = 0; cp < NCOPY; ++cp){
            s  += __hip_atomic_load(&accum[cp*256 + t],       __ATOMIC_RELAXED, __HIP_MEMORY_SCOPE_AGENT);
            qq += __hip_atomic_load(&accum[cp*256 + 128 + t], __ATOMIC_RELAXED, __HIP_MEMORY_SCOPE_AGENT);
        }
        double mean = s / (double)NROWS;
        double var  = qq / (double)NROWS - mean*mean;
        double rs = 1.0 / sqrt(var + 1e-5);
        double scv = (double)g[t] * rs;
        scsh[t]       = (float)scv;
        scsh[nch + t] = (float)((double)be[t] - mean*scv);
    }
}

// 64-bit max with a DPP-moved partner; masked-off / invalid lanes receive 0,
// which never wins (low word of a real key is ~idx >= 0xFFFFF000 != 0).
#define DPPMAX64(key, ctrl, rmask)                                             \
    {                                                                          \
        uint32_t _lo = (uint32_t)(key), _hi = (uint32_t)((key) >> 32);         \
        uint32_t _olo = (uint32_t)__builtin_amdgcn_update_dpp(                 \
            0, (int)_lo, (ctrl), (rmask), 0xf, true);                          \
        uint32_t _ohi = (uint32_t)__builtin_amdgcn_update_dpp(                 \
            0, (int)_hi, (ctrl), (rmask), 0xf, true);                          \
        unsigned long long _o = (((unsigned long long)_ohi) << 32) | _olo;     \
        key = (_o > (key)) ? _o : (key);                                       \
    }

// ---------------------------------------------------------------- mega-kernel shared union
// One static LDS union sized >80KB forces 1 block/CU for EVERY block of the
// mega-kernel -> fps blocks own their CU exclusively.
struct FpsSh {
    float LX[NPTS], LY[NPTS], LZ[NPTS];
    f32x4 SC[NS];
    alignas(16) unsigned long long cand[2][4];
};
struct WrkSh {
    float S_s[16][64], S_q[16][64];
    int   idxL[2][NK];
    f32x4 Lc[2];
};
union MegaSh { FpsSh f; WrkSh w; char force_one_block_per_cu[86016]; };

// ---------------------------------------------------------------- mega: fps (blocks 0..7) + qball/layer0 workers (blocks 8..4103)
// fps r10 loop VERBATIM except: (a) lgkm-only barrier (see BAR_LGKM comment),
// (b) publish on wave1 / SC-store on wave3 to balance per-wave serial burden.
// Serial floor: 1024 dependent argmax iters.
// Proven-regression list (do not retry): coord-carry cand (r5), float4 LDS
// coords (r8), 512 threads (r9), ballot owner-find / equality-mask argmax
// (r5, r11), helper-block fusion of prep/ptsconv (r12/r13).
// Proven wins: DPP-VALU u64 reduce (r3), pk-f32 distance (r10).
// DO NOT TOUCH the distance math: contract(off), a+(-c) == a-c IEEE —
// selection is bit-exact vs reference (verified r2-r13).
#define FT 16
__global__ __launch_bounds__(256) void mega_kernel(const float* __restrict__ xyz,
                                                   const float* __restrict__ pts,
                                                   const uint16_t* __restrict__ w0b,
                                                   const float* __restrict__ b0,
                                                   uint16_t* __restrict__ z0,
                                                   double* __restrict__ accumOut,
                                                   float* __restrict__ cent,
                                                   float* __restrict__ out_newxyz,
                                                   const float* __restrict__ g0,
                                                   const float* __restrict__ be0,
                                                   float* __restrict__ scsh0,
                                                   int* __restrict__ ticket0){
    __shared__ MegaSh sh;
    __shared__ int s_last;
    const int t = threadIdx.x;

    if (blockIdx.x < NB){
        // ------------------------------------------------ fps producer (1 block = 1 batch)
        const int b = blockIdx.x;
        const float* base = xyz + (size_t)b * (NPTS*3);
        f32x2 px2[FT/2], py2[FT/2], pz2[FT/2], pd2[FT/2];
#pragma unroll
        for (int j = 0; j < FT/2; ++j){
            int i = t*FT + 2*j;
            float x0 = base[i*3+0], y0 = base[i*3+1], z0c = base[i*3+2];
            float x1 = base[i*3+3], y1 = base[i*3+4], z1c = base[i*3+5];
            px2[j] = (f32x2){x0, x1};
            py2[j] = (f32x2){y0, y1};
            pz2[j] = (f32x2){z0c, z1c};
            pd2[j] = (f32x2){1e10f, 1e10f};
            sh.f.LX[i]=x0; sh.f.LY[i]=y0; sh.f.LZ[i]=z0c;
            sh.f.LX[i+1]=x1; sh.f.LY[i+1]=y1; sh.f.LZ[i+1]=z1c;
        }
        __syncthreads();
        int cur = 0;
        const int wave = t >> 6, lane = t & 63;
        for (int s = 0; s < NS; ++s){
            float cx = sh.f.LX[cur], cy = sh.f.LY[cur], cz = sh.f.LZ[cur];
            if (t == 64) publish_cent(cent, b*NS + s, cx, cy, cz);   // wave1: fire-and-forget
            if (t == 192) sh.f.SC[s] = (f32x4){cx, cy, cz, 0.f};     // wave3: local copy
            f32x2 ncx = (f32x2){-cx, -cx};
            f32x2 ncy = (f32x2){-cy, -cy};
            f32x2 ncz = (f32x2){-cz, -cz};
            float bestd = -1.0f; int besti = 0;
#pragma unroll
            for (int j = 0; j < FT/2; ++j){
                f32x2 d2;
                {
#pragma clang fp contract(off)
                    f32x2 dx = px2[j] + ncx;       // pk_add; == px - cx bit-exact
                    f32x2 dy = py2[j] + ncy;
                    f32x2 dz = pz2[j] + ncz;
                    f32x2 xx = dx*dx, yy = dy*dy, zz = dz*dz;   // pk_mul
                    d2 = (xx + yy) + zz;                        // pk_add x2
                }
                f32x2 nd;
                nd.x = fminf(pd2[j].x, d2.x);
                nd.y = fminf(pd2[j].y, d2.y);
                pd2[j] = nd;
                if (nd.x > bestd){ bestd = nd.x; besti = t*FT + 2*j; }
                if (nd.y > bestd){ bestd = nd.y; besti = t*FT + 2*j + 1; }
            }
            unsigned long long key =
                (((unsigned long long)__float_as_uint(bestd)) << 32) |
                (unsigned long long)(~(unsigned)besti);
            DPPMAX64(key, 0x111, 0xf);   // row_shr:1
            DPPMAX64(key, 0x112, 0xf);   // row_shr:2
            DPPMAX64(key, 0x114, 0xf);   // row_shr:4
            DPPMAX64(key, 0x118, 0xf);   // row_shr:8
            DPPMAX64(key, 0x142, 0xa);   // row_bcast:15 -> rows 1,3
            DPPMAX64(key, 0x143, 0xc);   // row_bcast:31 -> rows 2,3
            int p = s & 1;
            if (lane == 63) sh.f.cand[p][wave] = key;
            BAR_LGKM();                  // LDS-only barrier: publish store stays in flight
            ulonglong2 c01 = *reinterpret_cast<const ulonglong2*>(&sh.f.cand[p][0]);
            ulonglong2 c23 = *reinterpret_cast<const ulonglong2*>(&sh.f.cand[p][2]);
            unsigned long long m01 = (c01.x > c01.y) ? c01.x : c01.y;
            unsigned long long m23 = (c23.x > c23.y) ? c23.x : c23.y;
            unsigned long long km  = (m01 > m23) ? m01 : m23;
            cur = (int)(~(uint32_t)km);
        }
        __syncthreads();
        for (int i = t; i < NS; i += 256){
            f32x4 c = sh.f.SC[i];
            float* o = out_newxyz + ((size_t)b*NS + i)*3;
            o[0] = c[0]; o[1] = c[1]; o[2] = c[2];
        }
    } else {
        // ------------------------------------------------ worker: qball + layer0 for 2 cells
        // s-major ordering: worker w covers cells (b, 2*stile), (b, 2*stile+1)
        // with stile = w>>3, b = w&7 -> dispatch order == availability order.
        const int w = (int)blockIdx.x - NB;
        const int stile = w >> 3;
        const int b = w & 7;
        const int wave = t >> 6, lane = t & 63;
        const int q = lane >> 4, l16 = lane & 15;

        // prefetch weight fragments while fps produces our centroids
        bf16x8 Bf[4][3];
#pragma unroll
        for (int nt = 0; nt < 4; ++nt)
#pragma unroll
            for (int s = 0; s < 3; ++s)
                Bf[nt][s] = load_bf8(w0b + (nt*16 + l16)*96 + s*32 + q*8);

        if (t == 0){
            sh.w.Lc[0] = wait_cent(cent, b*NS + stile*2 + 0);
            sh.w.Lc[1] = wait_cent(cent, b*NS + stile*2 + 1);
        }
        __syncthreads();

        // qball: wave 0 -> cell0, wave 1 -> cell1 (verbatim scan, idx into LDS)
        if (wave < 2){
            f32x4 qc = sh.w.Lc[wave];
            float qx = qc[0], qy = qc[1], qz = qc[2];
            float qn = qx*qx;
            qn = fmaf(qy, qy, qn);
            qn = fmaf(qz, qz, qn);
            const float* base = xyz + (size_t)b * (NPTS*3);
            int cnt = 0, first = 0;
            for (int c0 = 0; c0 < NPTS; c0 += 64){
                int i = c0 + lane;
                float x = base[i*3+0], y = base[i*3+1], z = base[i*3+2];
                float xn = x*x;
                xn = fmaf(y, y, xn);
                xn = fmaf(z, z, xn);
                float dot = qx*x;
                dot = fmaf(qy, y, dot);
                dot = fmaf(qz, z, dot);
                float d;
                {
#pragma clang fp contract(off)
                    d = -2.0f * dot;
                    d = d + qn;
                    d = d + xn;
                }
                bool in = !(d > R2);
                unsigned long long m = __ballot(in);
                if (in){
                    int rank = __popcll(m & ((1ull << lane) - 1ull));
                    int pos = cnt + rank;
                    if (pos < NK) sh.w.idxL[wave][pos] = i;
                }
                if (cnt == 0 && m) first = c0 + (__ffsll((unsigned long long)m) - 1);
                cnt += __popcll(m);
                if (cnt >= NK) break;
            }
            if (cnt < NK){
                for (int p = cnt + lane; p < NK; p += 64) sh.w.idxL[wave][p] = first;
            }
        }
        __syncthreads();

        // layer0 body (identical math to the old layer0_mfma block)
        const int rowbase = (b*NS + stile*2)*NK;      // rows [rowbase, rowbase+64)
        const int r0 = rowbase + wave*16;
        const int cell = wave >> 1;
        const int sample = (wave & 1)*16 + l16;
        const int id = sh.w.idxL[cell][sample];
        const float* prow = pts + (((size_t)b << 12) + id)*64;
        const float* xr   = xyz + (((size_t)b << 12) + id)*3;
        f32x4 qc = sh.w.Lc[cell];
        float d0 = xr[0]-qc[0], d1 = xr[1]-qc[1], d2 = xr[2]-qc[2];

        f32x4 acc[4];
#pragma unroll
        for (int nt = 0; nt < 4; ++nt) acc[nt] = (f32x4){0.f,0.f,0.f,0.f};

#pragma unroll
        for (int s = 0; s < 3; ++s){
            const int k0 = s*32 + q*8;
            bf16x8 a;
#pragma unroll
            for (int j = 0; j < 8; ++j){
                int k = k0 + j;
                float v = (k < 3) ? ((k == 0) ? d0 : ((k == 1) ? d1 : d2))
                                  : ((k < 67) ? prow[k-3] : 0.f);
                a[j] = (short)f2bf(v);
            }
#pragma unroll
            for (int nt = 0; nt < 4; ++nt)
                acc[nt] = __builtin_amdgcn_mfma_f32_16x16x32_bf16(a, Bf[nt][s], acc[nt], 0, 0, 0);
        }
        // C/D: col=lane&15, row=quad*4+reg. Epilogue: bias, store, f32 stats partials.
#pragma unroll
        for (int nt = 0; nt < 4; ++nt){
            int c = nt*16 + l16;
            float bb = b0[c];
            float sps = 0.f, spq = 0.f;
#pragma unroll
            for (int reg = 0; reg < 4; ++reg){
                int rr = r0 + q*4 + reg;
                float h = acc[nt][reg] + bb;
                sps += h;
                spq = fmaf(h, h, spq);
                z0[(size_t)rr*64 + c] = f2bf(h);
            }
            sh.w.S_s[wave*4 + q][c] = sps;
            sh.w.S_q[wave*4 + q][c] = spq;
        }
        __syncthreads();
        if (t < 64){
            double ss = 0.0, sq = 0.0;
#pragma unroll
            for (int i = 0; i < 16; ++i){ ss += (double)sh.w.S_s[i][t]; sq += (double)sh.w.S_q[i][t]; }
            int cp = blockIdx.x & (NCOPY-1);
            atomicAdd(&accumOut[cp*256 + t], ss);
            atomicAdd(&accumOut[cp*256 + 128 + t], sq);
        }
        // last of 4096 workers computes layer-0 BN params once
        __threadfence();
        if (t == 0){
            int done = __hip_atomic_fetch_add(ticket0, 1, __ATOMIC_ACQ_REL, __HIP_MEMORY_SCOPE_AGENT);
            s_last = (done == 4096 - 1);
        }
        __syncthreads();
        if (s_last){
            __threadfence();
            compute_scsh(accumOut, g0, be0, 64, scsh0, t);
        }
    }
}

// ---------------------------------------------------------------- weight prep (fp32 -> bf16) + accum/ticket zeroing + cent flag clear
__global__ void prep_kernel(const float* __restrict__ w0, const float* __restrict__ w1,
                            const float* __restrict__ w2, uint16_t* __restrict__ w0b,
                            uint16_t* __restrict__ w1b, uint16_t* __restrict__ w2b,
                            double* __restrict__ accumAll, float* __restrict__ cent,
                            int* __restrict__ tickets){
    int t = blockIdx.x*256 + threadIdx.x;
    int stride = gridDim.x*256;
    if (t < 16) tickets[t] = 0;
    for (int i = t; i < 3*NCOPY*256; i += stride) accumAll[i] = 0.0;
    // clear centroid mailboxes (flag word must be 0 before mega workers poll;
    // kernel-boundary L2 writeback publishes these zeros to the coherent point)
    for (int i = t; i < NB*NS; i += stride)
        ((f32x4*)cent)[i] = (f32x4){0.f, 0.f, 0.f, 0.f};
    for (int i = t; i < 64*96; i += stride){
        int n = i/96, c = i%96;
        w0b[i] = (c < 67) ? f2bf(w0[n*67 + c]) : (uint16_t)0;
    }
    for (int i = t; i < 64*64; i += stride)  w1b[i] = f2bf(w1[i]);
    for (int i = t; i < 128*64; i += stride) w2b[i] = f2bf(w2[i]);
}

// ---------------------------------------------------------------- layer 1: BN(precomputed)+relu+GEMM K=64 + fused stats + last-block scsh1
__global__ __launch_bounds__(256) void layer1_mfma(const uint16_t* __restrict__ zin,
                                                   const float* __restrict__ scsh_in,
                                                   const uint16_t* __restrict__ wb,
                                                   const float* __restrict__ bias,
                                                   uint16_t* __restrict__ zout,
                                                   double* __restrict__ accumOut,
                                                   const float* __restrict__ g1,
                                                   const float* __restrict__ be1,
                                                   float* __restrict__ scsh_out,
                                                   int* __restrict__ ticket){
    constexpr int NT = 4;
    __shared__ float sc_l[64], sh_l[64];
    __shared__ float S_s[16][64], S_q[16][64];
    __shared__ int s_last;
    const int t = threadIdx.x;
    if (t < 64){ sc_l[t] = scsh_in[t]; sh_l[t] = scsh_in[64 + t]; }
    __syncthreads();

    const int wave = t >> 6, lane = t & 63;
    const int q = lane >> 4, l16 = lane & 15;
    const int r0 = blockIdx.x*64 + wave*16;

    bf16x8 Bf[NT][2];
#pragma unroll
    for (int nt = 0; nt < NT; ++nt)
#pragma unroll
        for (int s = 0; s < 2; ++s)
            Bf[nt][s] = load_bf8(wb + (nt*16 + l16)*64 + s*32 + q*8);

    float sc[2][8], sh[2][8];
#pragma unroll
    for (int s = 0; s < 2; ++s)
#pragma unroll
        for (int j = 0; j < 8; ++j){
            sc[s][j] = sc_l[s*32 + q*8 + j];
            sh[s][j] = sh_l[s*32 + q*8 + j];
        }

    f32x4 acc[NT];
#pragma unroll
    for (int nt = 0; nt < NT; ++nt) acc[nt] = (f32x4){0.f,0.f,0.f,0.f};

    const uint16_t* zr = zin + (size_t)(r0 + l16)*64;
#pragma unroll
    for (int s = 0; s < 2; ++s){
        uint4 u = *reinterpret_cast<const uint4*>(zr + s*32 + q*8);
        float h[8];
        h[0] = bf2f((uint16_t)(u.x & 0xFFFF)); h[1] = bf2f((uint16_t)(u.x >> 16));
        h[2] = bf2f((uint16_t)(u.y & 0xFFFF)); h[3] = bf2f((uint16_t)(u.y >> 16));
        h[4] = bf2f((uint16_t)(u.z & 0xFFFF)); h[5] = bf2f((uint16_t)(u.z >> 16));
        h[6] = bf2f((uint16_t)(u.w & 0xFFFF)); h[7] = bf2f((uint16_t)(u.w >> 16));
        bf16x8 a;
#pragma unroll
        for (int j = 0; j < 8; ++j){
            float v = fmaxf(fmaf(h[j], sc[s][j], sh[s][j]), 0.f);
            a[j] = (short)f2bf(v);
        }
#pragma unroll
        for (int nt = 0; nt < NT; ++nt)
            acc[nt] = __builtin_amdgcn_mfma_f32_16x16x32_bf16(a, Bf[nt][s], acc[nt], 0, 0, 0);
    }
#pragma unroll
    for (int nt = 0; nt < NT; ++nt){
        int c = nt*16 + l16;
        float bb = bias[c];
        float sps = 0.f, spq = 0.f;
#pragma unroll
        for (int reg = 0; reg < 4; ++reg){
            int rr = r0 + q*4 + reg;
            float h = acc[nt][reg] + bb;
            sps += h;
            spq = fmaf(h, h, spq);
            zout[(size_t)rr*64 + c] = f2bf(h);
        }
        S_s[wave*4 + q][c] = sps;
        S_q[wave*4 + q][c] = spq;
    }
    __syncthreads();
    if (t < 64){
        double ss = 0.0, sq = 0.0;
#pragma unroll
        for (int i = 0; i < 16; ++i){ ss += (double)S_s[i][t]; sq += (double)S_q[i][t]; }
        int cp = blockIdx.x & (NCOPY-1);
        atomicAdd(&accumOut[cp*256 + t], ss);
        atomicAdd(&accumOut[cp*256 + 128 + t], sq);
    }
    __threadfence();
    if (t == 0){
        int done = __hip_atomic_fetch_add(ticket, 1, __ATOMIC_ACQ_REL, __HIP_MEMORY_SCOPE_AGENT);
        s_last = (done == 4096 - 1);
    }
    __syncthreads();
    if (s_last){
        __threadfence();
        compute_scsh(accumOut, g1, be1, 64, scsh_out, t);
    }
}

// ---------------------------------------------------------------- layer 2: BN(precomputed)+relu+GEMM K=64 -> 128 + fused stats + pooling + last-block scsh2
__global__ __launch_bounds__(256) void layer2_mfma(const uint16_t* __restrict__ zin,
                                                   const float* __restrict__ scsh_in,
                                                   const uint16_t* __restrict__ wb,
                                                   const float* __restrict__ bias,
                                                   float2* __restrict__ pool,
                                                   double* __restrict__ accumOut,
                                                   const float* __restrict__ g2,
                                                   const float* __restrict__ be2,
                                                   float* __restrict__ scsh_out,
                                                   int* __restrict__ ticket){
    constexpr int NT = 8;
    __shared__ float sc_l[64], sh_l[64];
    __shared__ float S_s[16][128], S_q[16][128];
    __shared__ float P_mx[16][128], P_mn[16][128];
    __shared__ int s_last;
    const int t = threadIdx.x;
    if (t < 64){ sc_l[t] = scsh_in[t]; sh_l[t] = scsh_in[64 + t]; }
    __syncthreads();

    const int wave = t >> 6, lane = t & 63;
    const int q = lane >> 4, l16 = lane & 15;
    const int r0 = blockIdx.x*64 + wave*16;

    bf16x8 Bf[NT][2];
#pragma unroll
    for (int nt = 0; nt < NT; ++nt)
#pragma unroll
        for (int s = 0; s < 2; ++s)
            Bf[nt][s] = load_bf8(wb + (nt*16 + l16)*64 + s*32 + q*8);

    float sc[2][8], sh[2][8];
#pragma unroll
    for (int s = 0; s < 2; ++s)
#pragma unroll
        for (int j = 0; j < 8; ++j){
            sc[s][j] = sc_l[s*32 + q*8 + j];
            sh[s][j] = sh_l[s*32 + q*8 + j];
        }

    f32x4 acc[NT];
#pragma unroll
    for (int nt = 0; nt < NT; ++nt) acc[nt] = (f32x4){0.f,0.f,0.f,0.f};

    const uint16_t* zr = zin + (size_t)(r0 + l16)*64;
#pragma unroll
    for (int s = 0; s < 2; ++s){
        uint4 u = *reinterpret_cast<const uint4*>(zr + s*32 + q*8);
        float h[8];
        h[0] = bf2f((uint16_t)(u.x & 0xFFFF)); h[1] = bf2f((uint16_t)(u.x >> 16));
        h[2] = bf2f((uint16_t)(u.y & 0xFFFF)); h[3] = bf2f((uint16_t)(u.y >> 16));
        h[4] = bf2f((uint16_t)(u.z & 0xFFFF)); h[5] = bf2f((uint16_t)(u.z >> 16));
        h[6] = bf2f((uint16_t)(u.w & 0xFFFF)); h[7] = bf2f((uint16_t)(u.w >> 16));
        bf16x8 a;
#pragma unroll
        for (int j = 0; j < 8; ++j){
            float v = fmaxf(fmaf(h[j], sc[s][j], sh[s][j]), 0.f);
            a[j] = (short)f2bf(v);
        }
#pragma unroll
        for (int nt = 0; nt < NT; ++nt)
            acc[nt] = __builtin_amdgcn_mfma_f32_16x16x32_bf16(a, Bf[nt][s], acc[nt], 0, 0, 0);
    }
#pragma unroll
    for (int nt = 0; nt < NT; ++nt){
        int c = nt*16 + l16;
        float bb = bias[c];
        float sps = 0.f, spq = 0.f;
        float mx = -1e30f, mn = 1e30f;
#pragma unroll
        for (int reg = 0; reg < 4; ++reg){
            float h = acc[nt][reg] + bb;
            sps += h;
            spq = fmaf(h, h, spq);
            mx = fmaxf(mx, h);
            mn = fminf(mn, h);
        }
        S_s[wave*4 + q][c] = sps;
        S_q[wave*4 + q][c] = spq;
        P_mx[wave*4 + q][c] = mx;
        P_mn[wave*4 + q][c] = mn;
    }
    __syncthreads();
    if (t < 128){
        double ss = 0.0, sq = 0.0;
#pragma unroll
        for (int i = 0; i < 16; ++i){ ss += (double)S_s[i][t]; sq += (double)S_q[i][t]; }
        int cp = blockIdx.x & (NCOPY-1);
        atomicAdd(&accumOut[cp*256 + t], ss);
        atomicAdd(&accumOut[cp*256 + 128 + t], sq);
    }
    {
        int gidx = t >> 7;          // 0..1
        int c = t & 127;
        float mx = -1e30f, mn = 1e30f;
#pragma unroll
        for (int i = 0; i < 8; ++i){
            mx = fmaxf(mx, P_mx[gidx*8 + i][c]);
            mn = fminf(mn, P_mn[gidx*8 + i][c]);
        }
        pool[(size_t)(blockIdx.x*2 + gidx)*128 + c] = make_float2(mx, mn);
    }
    __threadfence();
    if (t == 0){
        int done = __hip_atomic_fetch_add(ticket, 1, __ATOMIC_ACQ_REL, __HIP_MEMORY_SCOPE_AGENT);
        s_last = (done == 4096 - 1);
    }
    __syncthreads();
    if (s_last){
        __threadfence();
        compute_scsh(accumOut, g2, be2, 128, scsh_out, t);
    }
}

// ---------------------------------------------------------------- final: BN(precomputed) + select max/min by sign(scale) + relu + transpose
__global__ __launch_bounds__(256) void final_kernel(const float2* __restrict__ pool,
                                                    const float* __restrict__ scsh_in,
                                                    float* __restrict__ out){
    __shared__ float sc_l[128], sh_l[128];
    const int t0 = threadIdx.x;
    if (t0 < 128){ sc_l[t0] = scsh_in[t0]; sh_l[t0] = scsh_in[128 + t0]; }
    __syncthreads();

    int t = blockIdx.x*256 + threadIdx.x;   // 1048576 == pool linear index
    int o = t & 127;
    int s = (t >> 7) & 1023;
    int b = t >> 17;
    float2 p = pool[t];
    float sc = sc_l[o], sh = sh_l[o];
    float zsel = (sc >= 0.f) ? p.x : p.y;
    float y = fmaxf(fmaf(zsel, sc, sh), 0.f);
    out[24576 + ((size_t)b << 17) + ((size_t)o << 10) + s] = y;
}

// ---------------------------------------------------------------- launch
extern "C" void kernel_launch(void* const* d_in, const int* in_sizes, int n_in,
                              void* d_out, int out_size, void* d_ws, size_t ws_size,
                              hipStream_t stream) {
    const float* xyz = (const float*)d_in[0];
    const float* pts = (const float*)d_in[1];
    const float* w0  = (const float*)d_in[2];
    const float* b0  = (const float*)d_in[3];
    const float* g0  = (const float*)d_in[4];
    const float* be0 = (const float*)d_in[5];
    const float* w1  = (const float*)d_in[6];
    const float* b1  = (const float*)d_in[7];
    const float* g1  = (const float*)d_in[8];
    const float* be1 = (const float*)d_in[9];
    const float* w2  = (const float*)d_in[10];
    const float* b2  = (const float*)d_in[11];
    const float* g2  = (const float*)d_in[12];
    const float* be2 = (const float*)d_in[13];
    float* out = (float*)d_out;

    char* ws = (char*)d_ws;
    // accum: 3 layers x NCOPY x 256 doubles = 196608 B
    double*   accum0 = (double*)(ws + 0);
    double*   accum1 = (double*)(ws + 65536);
    double*   accum2 = (double*)(ws + 131072);
    uint16_t* w0b    = (uint16_t*)(ws + 196608);    // 12288 B
    uint16_t* w1b    = (uint16_t*)(ws + 208896);    // 8192 B
    uint16_t* w2b    = (uint16_t*)(ws + 217088);    // 16384 B
    uint16_t* z0     = (uint16_t*)(ws + 262144);    // 33554432 B
    uint16_t* z1     = (uint16_t*)(ws + 33816576);  // 33554432 B
    float2*   pool   = (float2*)  (ws + 67371008);  // 8388608 B
    float*    cent   = (float*)   (ws + 75759616);  // 131072 B centroid mailboxes
    float*    scsh0  = (float*)   (ws + 75890688);  // 512 B  {scale[64], shift[64]}
    float*    scsh1  = (float*)   (ws + 75891200);  // 512 B
    float*    scsh2  = (float*)   (ws + 75891712);  // 1024 B {scale[128], shift[128]}
    int*      tickets= (int*)     (ws + 75892736);  // 64 B   (3 used)

    prep_kernel<<<32, 256, 0, stream>>>(w0, w1, w2, w0b, w1b, w2b, accum0, cent, tickets);
    // mega: blocks 0..7 = fps producers; blocks 8..4103 = qball+layer0 workers
    // overlapped under the fps serial shadow; last worker folds BN0 params.
    mega_kernel<<<NB + 4096, 256, 0, stream>>>(xyz, pts, w0b, b0, z0, accum0, cent, out,
                                               g0, be0, scsh0, &tickets[0]);
    layer1_mfma<<<4096, 256, 0, stream>>>(z0, scsh0, w1b, b1, z1, accum1,
                                          g1, be1, scsh1, &tickets[1]);
    layer2_mfma<<<4096, 256, 0, stream>>>(z1, scsh1, w2b, b2, pool, accum2,
                                          g2, be2, scsh2, &tickets[2]);
    final_kernel<<<4096, 256, 0, stream>>>(pool, scsh2, out);
}

// Round 3
// 804.872 us; speedup vs baseline: 2.1450x; 2.1450x over previous
//
#include <hip/hip_runtime.h>
#include <stdint.h>

#define NB 8
#define NPTS 4096
#define NS 1024
#define NK 32
#define NROWS (NB*NS*NK)   // 262144
#define R2 0.04f
#define NCOPY 32           // atomic spreading copies for stats accum

typedef __attribute__((ext_vector_type(8))) short bf16x8;   // 8 bf16 in 4 VGPRs
typedef __attribute__((ext_vector_type(4))) float f32x4;    // MFMA 16x16 accumulator
typedef __attribute__((ext_vector_type(2))) float f32x2;    // packed fp32 (v_pk_*)

__device__ __forceinline__ float bf2f(uint16_t u){
    uint32_t v = ((uint32_t)u) << 16;
    return __uint_as_float(v);
}
__device__ __forceinline__ uint16_t f2bf(float f){
    uint32_t u = __float_as_uint(f);
    uint32_t r = (u + 0x7FFFu + ((u >> 16) & 1u)) >> 16;
    return (uint16_t)r;
}
__device__ __forceinline__ bf16x8 load_bf8(const uint16_t* p){
    return *reinterpret_cast<const bf16x8*>(p);
}

// LDS-only barrier: waits ds ops (cand exchange) but does NOT drain outstanding
// global stores (the per-iteration publish). __syncthreads() would emit
// s_waitcnt vmcnt(0) before s_barrier, putting the publish store's coherence-
// point ack latency on the fps serial critical path every iteration.
// LESSON (r2): per-block device-scope fences / acq_rel atomics are POISON on
// gfx950 (L2 wb/inv storm, +900us over 8k blocks). Plain atomicAdd is fine.
#define BAR_LGKM() asm volatile("s_waitcnt lgkmcnt(0)\n\ts_barrier" ::: "memory")

// ---------------------------------------------------------------- producer/consumer plumbing
// Centroid publish: ONE 16B L2-bypass store {x,y,z,flag=1.0f}. sc0+sc1 makes the
// store visible at the coherent point past the non-coherent per-XCD L2s.
// Flag travels in the same 16B transaction as the coords -> no vmcnt wait, no
// release fence needed on the (latency-critical) fps wave.
__device__ __forceinline__ void publish_cent(float* cent, int cell,
                                             float cx, float cy, float cz){
    f32x4 v; v[0] = cx; v[1] = cy; v[2] = cz; v[3] = 1.0f;
    unsigned long long a = (unsigned long long)(uintptr_t)(cent + (size_t)cell*4);
    asm volatile("global_store_dwordx4 %0, %1, off sc0 sc1"
                 :: "v"(a), "v"(v) : "memory");
}
// Consumer: poll the flag word with an agent-scope relaxed load (bypasses stale
// L2), s_sleep between polls; once set, re-read the full 16B with a bypass load.
__device__ __forceinline__ f32x4 wait_cent(const float* cent, int cell){
    const uint32_t* wp = (const uint32_t*)(cent + (size_t)cell*4) + 3;
    while (__hip_atomic_load(wp, __ATOMIC_RELAXED, __HIP_MEMORY_SCOPE_AGENT)
           != 0x3F800000u)
        __builtin_amdgcn_s_sleep(32);
    f32x4 r;
    unsigned long long a = (unsigned long long)(uintptr_t)(cent + (size_t)cell*4);
    asm volatile("global_load_dwordx4 %0, %1, off sc0 sc1\n\ts_waitcnt vmcnt(0)"
                 : "=v"(r) : "v"(a) : "memory");
    return r;
}

// 64-bit max with a DPP-moved partner; masked-off / invalid lanes receive 0,
// which never wins (low word of a real key is ~idx >= 0xFFFFF000 != 0).
#define DPPMAX64(key, ctrl, rmask)                                             \
    {                                                                          \
        uint32_t _lo = (uint32_t)(key), _hi = (uint32_t)((key) >> 32);         \
        uint32_t _olo = (uint32_t)__builtin_amdgcn_update_dpp(                 \
            0, (int)_lo, (ctrl), (rmask), 0xf, true);                          \
        uint32_t _ohi = (uint32_t)__builtin_amdgcn_update_dpp(                 \
            0, (int)_hi, (ctrl), (rmask), 0xf, true);                          \
        unsigned long long _o = (((unsigned long long)_ohi) << 32) | _olo;     \
        key = (_o > (key)) ? _o : (key);                                       \
    }

// ---------------------------------------------------------------- mega-kernel shared union
// One static LDS union sized >80KB forces 1 block/CU for EVERY block of the
// mega-kernel -> fps blocks own their CU exclusively.
struct FpsSh {
    float LX[NPTS], LY[NPTS], LZ[NPTS];
    f32x4 SC[NS];
    alignas(16) unsigned long long cand[2][4];
};
struct WrkSh {
    float S_s[16][64], S_q[16][64];
    int   idxL[2][NK];
    f32x4 Lc[2];
};
union MegaSh { FpsSh f; WrkSh w; char force_one_block_per_cu[86016]; };

// ---------------------------------------------------------------- mega: fps (blocks 0..7) + qball/layer0 workers (blocks 8..4103)
// fps r10 loop VERBATIM except: (a) lgkm-only barrier (see BAR_LGKM comment),
// (b) publish on wave1 / SC-store on wave3 to balance per-wave serial burden.
// Serial floor: 1024 dependent argmax iters.
// Proven-regression list (do not retry): coord-carry cand (r5), float4 LDS
// coords (r8), 512 threads (r9), ballot owner-find / equality-mask argmax
// (r5, r11), helper-block fusion of prep/ptsconv (r12/r13), per-block
// device-scope fence/ticket tails (R2 of this session: +900us).
// Proven wins: DPP-VALU u64 reduce (r3), pk-f32 distance (r10).
// DO NOT TOUCH the distance math: contract(off), a+(-c) == a-c IEEE —
// selection is bit-exact vs reference (verified r2-r13).
#define FT 16
__global__ __launch_bounds__(256) void mega_kernel(const float* __restrict__ xyz,
                                                   const float* __restrict__ pts,
                                                   const uint16_t* __restrict__ w0b,
                                                   const float* __restrict__ b0,
                                                   uint16_t* __restrict__ z0,
                                                   double* __restrict__ accumOut,
                                                   float* __restrict__ cent,
                                                   float* __restrict__ out_newxyz){
    __shared__ MegaSh sh;
    const int t = threadIdx.x;

    if (blockIdx.x < NB){
        // ------------------------------------------------ fps producer (1 block = 1 batch)
        const int b = blockIdx.x;
        const float* base = xyz + (size_t)b * (NPTS*3);
        f32x2 px2[FT/2], py2[FT/2], pz2[FT/2], pd2[FT/2];
#pragma unroll
        for (int j = 0; j < FT/2; ++j){
            int i = t*FT + 2*j;
            float x0 = base[i*3+0], y0 = base[i*3+1], z0c = base[i*3+2];
            float x1 = base[i*3+3], y1 = base[i*3+4], z1c = base[i*3+5];
            px2[j] = (f32x2){x0, x1};
            py2[j] = (f32x2){y0, y1};
            pz2[j] = (f32x2){z0c, z1c};
            pd2[j] = (f32x2){1e10f, 1e10f};
            sh.f.LX[i]=x0; sh.f.LY[i]=y0; sh.f.LZ[i]=z0c;
            sh.f.LX[i+1]=x1; sh.f.LY[i+1]=y1; sh.f.LZ[i+1]=z1c;
        }
        __syncthreads();
        int cur = 0;
        const int wave = t >> 6, lane = t & 63;
        for (int s = 0; s < NS; ++s){
            float cx = sh.f.LX[cur], cy = sh.f.LY[cur], cz = sh.f.LZ[cur];
            if (t == 64) publish_cent(cent, b*NS + s, cx, cy, cz);   // wave1: fire-and-forget
            if (t == 192) sh.f.SC[s] = (f32x4){cx, cy, cz, 0.f};     // wave3: local copy
            f32x2 ncx = (f32x2){-cx, -cx};
            f32x2 ncy = (f32x2){-cy, -cy};
            f32x2 ncz = (f32x2){-cz, -cz};
            float bestd = -1.0f; int besti = 0;
#pragma unroll
            for (int j = 0; j < FT/2; ++j){
                f32x2 d2;
                {
#pragma clang fp contract(off)
                    f32x2 dx = px2[j] + ncx;       // pk_add; == px - cx bit-exact
                    f32x2 dy = py2[j] + ncy;
                    f32x2 dz = pz2[j] + ncz;
                    f32x2 xx = dx*dx, yy = dy*dy, zz = dz*dz;   // pk_mul
                    d2 = (xx + yy) + zz;                        // pk_add x2
                }
                f32x2 nd;
                nd.x = fminf(pd2[j].x, d2.x);
                nd.y = fminf(pd2[j].y, d2.y);
                pd2[j] = nd;
                if (nd.x > bestd){ bestd = nd.x; besti = t*FT + 2*j; }
                if (nd.y > bestd){ bestd = nd.y; besti = t*FT + 2*j + 1; }
            }
            unsigned long long key =
                (((unsigned long long)__float_as_uint(bestd)) << 32) |
                (unsigned long long)(~(unsigned)besti);
            DPPMAX64(key, 0x111, 0xf);   // row_shr:1
            DPPMAX64(key, 0x112, 0xf);   // row_shr:2
            DPPMAX64(key, 0x114, 0xf);   // row_shr:4
            DPPMAX64(key, 0x118, 0xf);   // row_shr:8
            DPPMAX64(key, 0x142, 0xa);   // row_bcast:15 -> rows 1,3
            DPPMAX64(key, 0x143, 0xc);   // row_bcast:31 -> rows 2,3
            int p = s & 1;
            if (lane == 63) sh.f.cand[p][wave] = key;
            BAR_LGKM();                  // LDS-only barrier: publish store stays in flight
            ulonglong2 c01 = *reinterpret_cast<const ulonglong2*>(&sh.f.cand[p][0]);
            ulonglong2 c23 = *reinterpret_cast<const ulonglong2*>(&sh.f.cand[p][2]);
            unsigned long long m01 = (c01.x > c01.y) ? c01.x : c01.y;
            unsigned long long m23 = (c23.x > c23.y) ? c23.x : c23.y;
            unsigned long long km  = (m01 > m23) ? m01 : m23;
            cur = (int)(~(uint32_t)km);
        }
        __syncthreads();
        for (int i = t; i < NS; i += 256){
            f32x4 c = sh.f.SC[i];
            float* o = out_newxyz + ((size_t)b*NS + i)*3;
            o[0] = c[0]; o[1] = c[1]; o[2] = c[2];
        }
    } else {
        // ------------------------------------------------ worker: qball + layer0 for 2 cells
        // s-major ordering: worker w covers cells (b, 2*stile), (b, 2*stile+1)
        // with stile = w>>3, b = w&7 -> dispatch order == availability order.
        const int w = (int)blockIdx.x - NB;
        const int stile = w >> 3;
        const int b = w & 7;
        const int wave = t >> 6, lane = t & 63;
        const int q = lane >> 4, l16 = lane & 15;

        // prefetch weight fragments while fps produces our centroids
        bf16x8 Bf[4][3];
#pragma unroll
        for (int nt = 0; nt < 4; ++nt)
#pragma unroll
            for (int s = 0; s < 3; ++s)
                Bf[nt][s] = load_bf8(w0b + (nt*16 + l16)*96 + s*32 + q*8);

        if (t == 0){
            sh.w.Lc[0] = wait_cent(cent, b*NS + stile*2 + 0);
            sh.w.Lc[1] = wait_cent(cent, b*NS + stile*2 + 1);
        }
        __syncthreads();

        // qball: wave 0 -> cell0, wave 1 -> cell1 (verbatim scan, idx into LDS)
        if (wave < 2){
            f32x4 qc = sh.w.Lc[wave];
            float qx = qc[0], qy = qc[1], qz = qc[2];
            float qn = qx*qx;
            qn = fmaf(qy, qy, qn);
            qn = fmaf(qz, qz, qn);
            const float* base = xyz + (size_t)b * (NPTS*3);
            int cnt = 0, first = 0;
            for (int c0 = 0; c0 < NPTS; c0 += 64){
                int i = c0 + lane;
                float x = base[i*3+0], y = base[i*3+1], z = base[i*3+2];
                float xn = x*x;
                xn = fmaf(y, y, xn);
                xn = fmaf(z, z, xn);
                float dot = qx*x;
                dot = fmaf(qy, y, dot);
                dot = fmaf(qz, z, dot);
                float d;
                {
#pragma clang fp contract(off)
                    d = -2.0f * dot;
                    d = d + qn;
                    d = d + xn;
                }
                bool in = !(d > R2);
                unsigned long long m = __ballot(in);
                if (in){
                    int rank = __popcll(m & ((1ull << lane) - 1ull));
                    int pos = cnt + rank;
                    if (pos < NK) sh.w.idxL[wave][pos] = i;
                }
                if (cnt == 0 && m) first = c0 + (__ffsll((unsigned long long)m) - 1);
                cnt += __popcll(m);
                if (cnt >= NK) break;
            }
            if (cnt < NK){
                for (int p = cnt + lane; p < NK; p += 64) sh.w.idxL[wave][p] = first;
            }
        }
        __syncthreads();

        // layer0 body (identical math to the old layer0_mfma block)
        const int rowbase = (b*NS + stile*2)*NK;      // rows [rowbase, rowbase+64)
        const int r0 = rowbase + wave*16;
        const int cell = wave >> 1;
        const int sample = (wave & 1)*16 + l16;
        const int id = sh.w.idxL[cell][sample];
        const float* prow = pts + (((size_t)b << 12) + id)*64;
        const float* xr   = xyz + (((size_t)b << 12) + id)*3;
        f32x4 qc = sh.w.Lc[cell];
        float d0 = xr[0]-qc[0], d1 = xr[1]-qc[1], d2 = xr[2]-qc[2];

        f32x4 acc[4];
#pragma unroll
        for (int nt = 0; nt < 4; ++nt) acc[nt] = (f32x4){0.f,0.f,0.f,0.f};

#pragma unroll
        for (int s = 0; s < 3; ++s){
            const int k0 = s*32 + q*8;
            bf16x8 a;
#pragma unroll
            for (int j = 0; j < 8; ++j){
                int k = k0 + j;
                float v = (k < 3) ? ((k == 0) ? d0 : ((k == 1) ? d1 : d2))
                                  : ((k < 67) ? prow[k-3] : 0.f);
                a[j] = (short)f2bf(v);
            }
#pragma unroll
            for (int nt = 0; nt < 4; ++nt)
                acc[nt] = __builtin_amdgcn_mfma_f32_16x16x32_bf16(a, Bf[nt][s], acc[nt], 0, 0, 0);
        }
        // C/D: col=lane&15, row=quad*4+reg. Epilogue: bias, store, f32 stats partials.
#pragma unroll
        for (int nt = 0; nt < 4; ++nt){
            int c = nt*16 + l16;
            float bb = b0[c];
            float sps = 0.f, spq = 0.f;
#pragma unroll
            for (int reg = 0; reg < 4; ++reg){
                int rr = r0 + q*4 + reg;
                float h = acc[nt][reg] + bb;
                sps += h;
                spq = fmaf(h, h, spq);
                z0[(size_t)rr*64 + c] = f2bf(h);
            }
            sh.w.S_s[wave*4 + q][c] = sps;
            sh.w.S_q[wave*4 + q][c] = spq;
        }
        __syncthreads();
        if (t < 64){
            double ss = 0.0, sq = 0.0;
#pragma unroll
            for (int i = 0; i < 16; ++i){ ss += (double)sh.w.S_s[i][t]; sq += (double)sh.w.S_q[i][t]; }
            int cp = blockIdx.x & (NCOPY-1);
            atomicAdd(&accumOut[cp*256 + t], ss);
            atomicAdd(&accumOut[cp*256 + 128 + t], sq);
        }
    }
}

// ---------------------------------------------------------------- weight prep (fp32 -> bf16) + accum zeroing + cent flag clear
__global__ void prep_kernel(const float* __restrict__ w0, const float* __restrict__ w1,
                            const float* __restrict__ w2, uint16_t* __restrict__ w0b,
                            uint16_t* __restrict__ w1b, uint16_t* __restrict__ w2b,
                            double* __restrict__ accumAll, float* __restrict__ cent){
    int t = blockIdx.x*256 + threadIdx.x;
    int stride = gridDim.x*256;
    for (int i = t; i < 3*NCOPY*256; i += stride) accumAll[i] = 0.0;
    // clear centroid mailboxes (flag word must be 0 before mega workers poll;
    // kernel-boundary L2 writeback publishes these zeros to the coherent point)
    for (int i = t; i < NB*NS; i += stride)
        ((f32x4*)cent)[i] = (f32x4){0.f, 0.f, 0.f, 0.f};
    for (int i = t; i < 64*96; i += stride){
        int n = i/96, c = i%96;
        w0b[i] = (c < 67) ? f2bf(w0[n*67 + c]) : (uint16_t)0;
    }
    for (int i = t; i < 64*64; i += stride)  w1b[i] = f2bf(w1[i]);
    for (int i = t; i < 128*64; i += stride) w2b[i] = f2bf(w2[i]);
}

// ---------------------------------------------------------------- layer 1: inline BN-param + BN+relu+GEMM K=64 + fused stats
// TPB=4 row-tiles per block (grid 1024): amortizes the NCOPY double-reduce
// preamble and weight/param loads 4x, and collapses stats atomics 4x
// (register-carried double partials, one atomicAdd at the end). NO fences.
__global__ __launch_bounds__(256) void layer1_mfma(const uint16_t* __restrict__ zin,
                                                   const double* __restrict__ accumIn,
                                                   const float* __restrict__ g,
                                                   const float* __restrict__ be,
                                                   const uint16_t* __restrict__ wb,
                                                   const float* __restrict__ bias,
                                                   uint16_t* __restrict__ zout,
                                                   double* __restrict__ accumOut){
    constexpr int NT = 4;
    constexpr int TPB = 4;
    __shared__ float sc_l[64], sh_l[64];
    __shared__ float S_s[16][64], S_q[16][64];
    const int t = threadIdx.x;
    if (t < 64){
        double s = 0.0, qq = 0.0;
#pragma unroll
        for (int cp = 0; cp < NCOPY; ++cp){
            s  += accumIn[cp*256 + t];
            qq += accumIn[cp*256 + 128 + t];
        }
        double mean = s / (double)NROWS;
        double var  = qq / (double)NROWS - mean*mean;
        double rs = 1.0 / sqrt(var + 1e-5);
        double scv = (double)g[t] * rs;
        sc_l[t] = (float)scv;
        sh_l[t] = (float)((double)be[t] - mean*scv);
    }
    __syncthreads();

    const int wave = t >> 6, lane = t & 63;
    const int q = lane >> 4, l16 = lane & 15;

    bf16x8 Bf[NT][2];
#pragma unroll
    for (int nt = 0; nt < NT; ++nt)
#pragma unroll
        for (int s = 0; s < 2; ++s)
            Bf[nt][s] = load_bf8(wb + (nt*16 + l16)*64 + s*32 + q*8);

    float sc[2][8], sh[2][8];
#pragma unroll
    for (int s = 0; s < 2; ++s)
#pragma unroll
        for (int j = 0; j < 8; ++j){
            sc[s][j] = sc_l[s*32 + q*8 + j];
            sh[s][j] = sh_l[s*32 + q*8 + j];
        }

    double accS = 0.0, accQ = 0.0;   // t<64 cross-tile stats partials

    for (int tile = 0; tile < TPB; ++tile){
        const int r0 = (blockIdx.x*TPB + tile)*64 + wave*16;

        f32x4 acc[NT];
#pragma unroll
        for (int nt = 0; nt < NT; ++nt) acc[nt] = (f32x4){0.f,0.f,0.f,0.f};

        const uint16_t* zr = zin + (size_t)(r0 + l16)*64;
#pragma unroll
        for (int s = 0; s < 2; ++s){
            uint4 u = *reinterpret_cast<const uint4*>(zr + s*32 + q*8);
            float h[8];
            h[0] = bf2f((uint16_t)(u.x & 0xFFFF)); h[1] = bf2f((uint16_t)(u.x >> 16));
            h[2] = bf2f((uint16_t)(u.y & 0xFFFF)); h[3] = bf2f((uint16_t)(u.y >> 16));
            h[4] = bf2f((uint16_t)(u.z & 0xFFFF)); h[5] = bf2f((uint16_t)(u.z >> 16));
            h[6] = bf2f((uint16_t)(u.w & 0xFFFF)); h[7] = bf2f((uint16_t)(u.w >> 16));
            bf16x8 a;
#pragma unroll
            for (int j = 0; j < 8; ++j){
                float v = fmaxf(fmaf(h[j], sc[s][j], sh[s][j]), 0.f);
                a[j] = (short)f2bf(v);
            }
#pragma unroll
            for (int nt = 0; nt < NT; ++nt)
                acc[nt] = __builtin_amdgcn_mfma_f32_16x16x32_bf16(a, Bf[nt][s], acc[nt], 0, 0, 0);
        }
#pragma unroll
        for (int nt = 0; nt < NT; ++nt){
            int c = nt*16 + l16;
            float bb = bias[c];
            float sps = 0.f, spq = 0.f;
#pragma unroll
            for (int reg = 0; reg < 4; ++reg){
                int rr = r0 + q*4 + reg;
                float h = acc[nt][reg] + bb;
                sps += h;
                spq = fmaf(h, h, spq);
                zout[(size_t)rr*64 + c] = f2bf(h);
            }
            S_s[wave*4 + q][c] = sps;
            S_q[wave*4 + q][c] = spq;
        }
        __syncthreads();
        if (t < 64){
#pragma unroll
            for (int i = 0; i < 16; ++i){ accS += (double)S_s[i][t]; accQ += (double)S_q[i][t]; }
        }
        __syncthreads();
    }
    if (t < 64){
        int cp = blockIdx.x & (NCOPY-1);
        atomicAdd(&accumOut[cp*256 + t], accS);
        atomicAdd(&accumOut[cp*256 + 128 + t], accQ);
    }
}

// ---------------------------------------------------------------- layer 2: BN+relu+GEMM K=64 -> 128 + fused stats + fused max/min POOLING
// TPB=4 tiles per block (grid 1024); per-tile pooling epilogue unchanged.
__global__ __launch_bounds__(256) void layer2_mfma(const uint16_t* __restrict__ zin,
                                                   const double* __restrict__ accumIn,
                                                   const float* __restrict__ g,
                                                   const float* __restrict__ be,
                                                   const uint16_t* __restrict__ wb,
                                                   const float* __restrict__ bias,
                                                   float2* __restrict__ pool,
                                                   double* __restrict__ accumOut){
    constexpr int NT = 8;
    constexpr int TPB = 4;
    __shared__ float sc_l[64], sh_l[64];
    __shared__ float S_s[16][128], S_q[16][128];
    __shared__ float P_mx[16][128], P_mn[16][128];
    const int t = threadIdx.x;
    if (t < 64){
        double s = 0.0, qq = 0.0;
#pragma unroll
        for (int cp = 0; cp < NCOPY; ++cp){
            s  += accumIn[cp*256 + t];
            qq += accumIn[cp*256 + 128 + t];
        }
        double mean = s / (double)NROWS;
        double var  = qq / (double)NROWS - mean*mean;
        double rs = 1.0 / sqrt(var + 1e-5);
        double scv = (double)g[t] * rs;
        sc_l[t] = (float)scv;
        sh_l[t] = (float)((double)be[t] - mean*scv);
    }
    __syncthreads();

    const int wave = t >> 6, lane = t & 63;
    const int q = lane >> 4, l16 = lane & 15;

    bf16x8 Bf[NT][2];
#pragma unroll
    for (int nt = 0; nt < NT; ++nt)
#pragma unroll
        for (int s = 0; s < 2; ++s)
            Bf[nt][s] = load_bf8(wb + (nt*16 + l16)*64 + s*32 + q*8);

    float sc[2][8], sh[2][8];
#pragma unroll
    for (int s = 0; s < 2; ++s)
#pragma unroll
        for (int j = 0; j < 8; ++j){
            sc[s][j] = sc_l[s*32 + q*8 + j];
            sh[s][j] = sh_l[s*32 + q*8 + j];
        }

    double accS = 0.0, accQ = 0.0;   // t<128 cross-tile stats partials

    for (int tile = 0; tile < TPB; ++tile){
        const int r0 = (blockIdx.x*TPB + tile)*64 + wave*16;

        f32x4 acc[NT];
#pragma unroll
        for (int nt = 0; nt < NT; ++nt) acc[nt] = (f32x4){0.f,0.f,0.f,0.f};

        const uint16_t* zr = zin + (size_t)(r0 + l16)*64;
#pragma unroll
        for (int s = 0; s < 2; ++s){
            uint4 u = *reinterpret_cast<const uint4*>(zr + s*32 + q*8);
            float h[8];
            h[0] = bf2f((uint16_t)(u.x & 0xFFFF)); h[1] = bf2f((uint16_t)(u.x >> 16));
            h[2] = bf2f((uint16_t)(u.y & 0xFFFF)); h[3] = bf2f((uint16_t)(u.y >> 16));
            h[4] = bf2f((uint16_t)(u.z & 0xFFFF)); h[5] = bf2f((uint16_t)(u.z >> 16));
            h[6] = bf2f((uint16_t)(u.w & 0xFFFF)); h[7] = bf2f((uint16_t)(u.w >> 16));
            bf16x8 a;
#pragma unroll
            for (int j = 0; j < 8; ++j){
                float v = fmaxf(fmaf(h[j], sc[s][j], sh[s][j]), 0.f);
                a[j] = (short)f2bf(v);
            }
#pragma unroll
            for (int nt = 0; nt < NT; ++nt)
                acc[nt] = __builtin_amdgcn_mfma_f32_16x16x32_bf16(a, Bf[nt][s], acc[nt], 0, 0, 0);
        }
#pragma unroll
        for (int nt = 0; nt < NT; ++nt){
            int c = nt*16 + l16;
            float bb = bias[c];
            float sps = 0.f, spq = 0.f;
            float mx = -1e30f, mn = 1e30f;
#pragma unroll
            for (int reg = 0; reg < 4; ++reg){
                float h = acc[nt][reg] + bb;
                sps += h;
                spq = fmaf(h, h, spq);
                mx = fmaxf(mx, h);
                mn = fminf(mn, h);
            }
            S_s[wave*4 + q][c] = sps;
            S_q[wave*4 + q][c] = spq;
            P_mx[wave*4 + q][c] = mx;
            P_mn[wave*4 + q][c] = mn;
        }
        __syncthreads();
        if (t < 128){
#pragma unroll
            for (int i = 0; i < 16; ++i){ accS += (double)S_s[i][t]; accQ += (double)S_q[i][t]; }
        }
        // pooling: each tile covers 2 groups of 32 rows (= 2 (b,s) cells)
        {
            int gidx = t >> 7;          // 0..1
            int c = t & 127;
            float mx = -1e30f, mn = 1e30f;
#pragma unroll
            for (int i = 0; i < 8; ++i){
                mx = fmaxf(mx, P_mx[gidx*8 + i][c]);
                mn = fminf(mn, P_mn[gidx*8 + i][c]);
            }
            pool[(size_t)((blockIdx.x*TPB + tile)*2 + gidx)*128 + c] = make_float2(mx, mn);
        }
        __syncthreads();
    }
    if (t < 128){
        int cp = blockIdx.x & (NCOPY-1);
        atomicAdd(&accumOut[cp*256 + t], accS);
        atomicAdd(&accumOut[cp*256 + 128 + t], accQ);
    }
}

// ---------------------------------------------------------------- final: inline BN-param + select max/min by sign(scale) + BN + relu + transpose
// Grid 1024, 4 chunks per block: amortizes the preamble 4x.
__global__ __launch_bounds__(256) void final_kernel(const float2* __restrict__ pool,
                                                    const double* __restrict__ accumIn,
                                                    const float* __restrict__ g,
                                                    const float* __restrict__ be,
                                                    float* __restrict__ out){
    __shared__ float sc_l[128], sh_l[128];
    const int t0 = threadIdx.x;
    if (t0 < 128){
        double s = 0.0, qq = 0.0;
#pragma unroll
        for (int cp = 0; cp < NCOPY; ++cp){
            s  += accumIn[cp*256 + t0];
            qq += accumIn[cp*256 + 128 + t0];
        }
        double mean = s / (double)NROWS;
        double var  = qq / (double)NROWS - mean*mean;
        double rs = 1.0 / sqrt(var + 1e-5);
        double scv = (double)g[t0] * rs;
        sc_l[t0] = (float)scv;
        sh_l[t0] = (float)((double)be[t0] - mean*scv);
    }
    __syncthreads();

#pragma unroll
    for (int it = 0; it < 4; ++it){
        int t = blockIdx.x*1024 + it*256 + threadIdx.x;   // 1048576 == pool linear index
        int o = t & 127;
        int s = (t >> 7) & 1023;
        int b = t >> 17;
        float2 p = pool[t];
        float sc = sc_l[o], sh = sh_l[o];
        float zsel = (sc >= 0.f) ? p.x : p.y;
        float y = fmaxf(fmaf(zsel, sc, sh), 0.f);
        out[24576 + ((size_t)b << 17) + ((size_t)o << 10) + s] = y;
    }
}

// ---------------------------------------------------------------- launch
extern "C" void kernel_launch(void* const* d_in, const int* in_sizes, int n_in,
                              void* d_out, int out_size, void* d_ws, size_t ws_size,
                              hipStream_t stream) {
    const float* xyz = (const float*)d_in[0];
    const float* pts = (const float*)d_in[1];
    const float* w0  = (const float*)d_in[2];
    const float* b0  = (const float*)d_in[3];
    const float* g0  = (const float*)d_in[4];
    const float* be0 = (const float*)d_in[5];
    const float* w1  = (const float*)d_in[6];
    const float* b1  = (const float*)d_in[7];
    const float* g1  = (const float*)d_in[8];
    const float* be1 = (const float*)d_in[9];
    const float* w2  = (const float*)d_in[10];
    const float* b2  = (const float*)d_in[11];
    const float* g2  = (const float*)d_in[12];
    const float* be2 = (const float*)d_in[13];
    float* out = (float*)d_out;

    char* ws = (char*)d_ws;
    // accum: 3 layers x NCOPY x 256 doubles = 196608 B
    double*   accum0 = (double*)(ws + 0);
    double*   accum1 = (double*)(ws + 65536);
    double*   accum2 = (double*)(ws + 131072);
    uint16_t* w0b    = (uint16_t*)(ws + 196608);    // 12288 B
    uint16_t* w1b    = (uint16_t*)(ws + 208896);    // 8192 B
    uint16_t* w2b    = (uint16_t*)(ws + 217088);    // 16384 B
    uint16_t* z0     = (uint16_t*)(ws + 262144);    // 33554432 B
    uint16_t* z1     = (uint16_t*)(ws + 33816576);  // 33554432 B
    float2*   pool   = (float2*)  (ws + 67371008);  // 8388608 B
    float*    cent   = (float*)   (ws + 75759616);  // 131072 B centroid mailboxes

    prep_kernel<<<32, 256, 0, stream>>>(w0, w1, w2, w0b, w1b, w2b, accum0, cent);
    // mega: blocks 0..7 = fps producers; blocks 8..4103 = qball+layer0 workers
    // overlapped under the fps serial shadow.
    mega_kernel<<<NB + 4096, 256, 0, stream>>>(xyz, pts, w0b, b0, z0, accum0, cent, out);
    layer1_mfma<<<1024, 256, 0, stream>>>(z0, accum0, g0, be0, w1b, b1, z1, accum1);
    layer2_mfma<<<1024, 256, 0, stream>>>(z1, accum1, g1, be1, w2b, b2, pool, accum2);
    final_kernel<<<1024, 256, 0, stream>>>(pool, accum2, g2, be2, out);
}

// Round 4
// 768.489 us; speedup vs baseline: 2.2465x; 1.0473x over previous
//
#include <hip/hip_runtime.h>
#include <stdint.h>

#define NB 8
#define NPTS 4096
#define NS 1024
#define NK 32
#define NROWS (NB*NS*NK)   // 262144
#define R2 0.04f
#define NCOPY 32           // atomic spreading copies for stats accum

typedef __attribute__((ext_vector_type(8))) short bf16x8;   // 8 bf16 in 4 VGPRs
typedef __attribute__((ext_vector_type(4))) float f32x4;    // MFMA 16x16 accumulator
typedef __attribute__((ext_vector_type(2))) float f32x2;    // packed fp32 (v_pk_*)

__device__ __forceinline__ float bf2f(uint16_t u){
    uint32_t v = ((uint32_t)u) << 16;
    return __uint_as_float(v);
}
__device__ __forceinline__ uint16_t f2bf(float f){
    uint32_t u = __float_as_uint(f);
    uint32_t r = (u + 0x7FFFu + ((u >> 16) & 1u)) >> 16;
    return (uint16_t)r;
}
__device__ __forceinline__ bf16x8 load_bf8(const uint16_t* p){
    return *reinterpret_cast<const bf16x8*>(p);
}

// SESSION LESSONS (measured):
//  - R2: per-block device-scope fences / acq_rel atomics are POISON on gfx950
//    (L2 wb/inv storm, +900us over 8k blocks). Plain atomicAdd is fine.
//  - R3: BAR_LGKM (inline-asm lgkm-only barrier) + wave-split publish REGRESSED
//    mega 635->668 vs plain __syncthreads + t0-publish. Keep __syncthreads.
//  - R3: TPB=4 tile amortization in layer1/2/final: downstream 182->137us. Keep.

// ---------------------------------------------------------------- producer/consumer plumbing
// Batched centroid publish: 4 cells per group, each cell ONE 16B L2-bypass
// store {x,y,z,flag=1.0f}. sc0+sc1 makes stores visible at the coherent point
// past the non-coherent per-XCD L2s. Flag travels in the same 16B transaction
// as its coords -> workers poll per-cell flags, no inter-store ordering needed.
// Issued at the TOP of the next group's first iteration: ~1360cyc of distance
// work precede the first __syncthreads drain -> store-ack latency fully hidden
// (r1's per-iter publish left ~120cyc/iter exposed = +52us).
__device__ __forceinline__ void publish_cent4(float* cent, int cell0,
                                              f32x4 c0, f32x4 c1, f32x4 c2, f32x4 c3){
    unsigned long long a = (unsigned long long)(uintptr_t)(cent + (size_t)cell0*4);
    asm volatile("global_store_dwordx4 %0, %1, off sc0 sc1\n\t"
                 "global_store_dwordx4 %0, %2, off offset:16 sc0 sc1\n\t"
                 "global_store_dwordx4 %0, %3, off offset:32 sc0 sc1\n\t"
                 "global_store_dwordx4 %0, %4, off offset:48 sc0 sc1"
                 :: "v"(a), "v"(c0), "v"(c1), "v"(c2), "v"(c3)
                 : "memory");
}
// Consumer: poll the flag word with an agent-scope relaxed load (bypasses stale
// L2), s_sleep between polls; once set, re-read the full 16B with a bypass load.
__device__ __forceinline__ f32x4 wait_cent(const float* cent, int cell){
    const uint32_t* wp = (const uint32_t*)(cent + (size_t)cell*4) + 3;
    while (__hip_atomic_load(wp, __ATOMIC_RELAXED, __HIP_MEMORY_SCOPE_AGENT)
           != 0x3F800000u)
        __builtin_amdgcn_s_sleep(64);   // r4: 64 (halve coherence-fabric poll traffic)
    f32x4 r;
    unsigned long long a = (unsigned long long)(uintptr_t)(cent + (size_t)cell*4);
    asm volatile("global_load_dwordx4 %0, %1, off sc0 sc1\n\ts_waitcnt vmcnt(0)"
                 : "=v"(r) : "v"(a) : "memory");
    return r;
}

// 64-bit max with a DPP-moved partner; masked-off / invalid lanes receive 0,
// which never wins (low word of a real key is ~idx >= 0xFFFFF000 != 0).
#define DPPMAX64(key, ctrl, rmask)                                             \
    {                                                                          \
        uint32_t _lo = (uint32_t)(key), _hi = (uint32_t)((key) >> 32);         \
        uint32_t _olo = (uint32_t)__builtin_amdgcn_update_dpp(                 \
            0, (int)_lo, (ctrl), (rmask), 0xf, true);                          \
        uint32_t _ohi = (uint32_t)__builtin_amdgcn_update_dpp(                 \
            0, (int)_hi, (ctrl), (rmask), 0xf, true);                          \
        unsigned long long _o = (((unsigned long long)_ohi) << 32) | _olo;     \
        key = (_o > (key)) ? _o : (key);                                       \
    }

// ---------------------------------------------------------------- mega-kernel shared union
// One static LDS union sized >80KB forces 1 block/CU for EVERY block of the
// mega-kernel -> fps blocks own their CU exclusively.
struct FpsSh {
    float LX[NPTS], LY[NPTS], LZ[NPTS];
    f32x4 SC[NS];
    alignas(16) unsigned long long cand[2][4];
};
struct WrkSh {
    float S_s[16][64], S_q[16][64];
    int   idxL[2][NK];
    f32x4 Lc[2];
};
union MegaSh { FpsSh f; WrkSh w; char force_one_block_per_cu[86016]; };

// ---------------------------------------------------------------- mega: fps (blocks 0..7) + qball/layer0 workers (blocks 8..4103)
// fps r10 loop VERBATIM (r1-session structure: __syncthreads barrier, t==0 does
// SC write; publish batched per-4 at group top — the ONLY change vs r1).
// Serial floor: 1024 dependent argmax iters.
// Proven-regression list (do not retry): coord-carry cand (r5), float4 LDS
// coords (r8), 512 threads (r9), ballot owner-find / equality-mask argmax
// (r5, r11), helper-block fusion of prep/ptsconv (r12/r13), per-block
// device-scope fence/ticket tails (R2: +900us), BAR_LGKM + wave-split (R3: +33us).
// Proven wins: DPP-VALU u64 reduce (r3), pk-f32 distance (r10).
// DO NOT TOUCH the distance math: contract(off), a+(-c) == a-c IEEE —
// selection is bit-exact vs reference (verified r2-r13).
#define FT 16
__global__ __launch_bounds__(256) void mega_kernel(const float* __restrict__ xyz,
                                                   const float* __restrict__ pts,
                                                   const uint16_t* __restrict__ w0b,
                                                   const float* __restrict__ b0,
                                                   uint16_t* __restrict__ z0,
                                                   double* __restrict__ accumOut,
                                                   float* __restrict__ cent,
                                                   float* __restrict__ out_newxyz){
    __shared__ MegaSh sh;
    const int t = threadIdx.x;

    if (blockIdx.x < NB){
        // ------------------------------------------------ fps producer (1 block = 1 batch)
        const int b = blockIdx.x;
        const float* base = xyz + (size_t)b * (NPTS*3);
        f32x2 px2[FT/2], py2[FT/2], pz2[FT/2], pd2[FT/2];
#pragma unroll
        for (int j = 0; j < FT/2; ++j){
            int i = t*FT + 2*j;
            float x0 = base[i*3+0], y0 = base[i*3+1], z0c = base[i*3+2];
            float x1 = base[i*3+3], y1 = base[i*3+4], z1c = base[i*3+5];
            px2[j] = (f32x2){x0, x1};
            py2[j] = (f32x2){y0, y1};
            pz2[j] = (f32x2){z0c, z1c};
            pd2[j] = (f32x2){1e10f, 1e10f};
            sh.f.LX[i]=x0; sh.f.LY[i]=y0; sh.f.LZ[i]=z0c;
            sh.f.LX[i+1]=x1; sh.f.LY[i+1]=y1; sh.f.LZ[i+1]=z1c;
        }
        __syncthreads();
        int cur = 0;
        const int wave = t >> 6, lane = t & 63;
        f32x4 pb0, pb1, pb2, pb3;    // previous group's centroids (lane 0 of wave 0)
        for (int s4 = 0; s4 < NS; s4 += 4){
            // publish the PREVIOUS group's 4 centroids; first barrier that can
            // drain these is a full iteration (~1360cyc) away -> ack hidden.
            if (s4 && t == 0)
                publish_cent4(cent, b*NS + (s4 - 4), pb0, pb1, pb2, pb3);
#pragma unroll
            for (int u = 0; u < 4; ++u){
                const int s = s4 + u;
                float cx = sh.f.LX[cur], cy = sh.f.LY[cur], cz = sh.f.LZ[cur];
                if (t == 0){
                    sh.f.SC[s] = (f32x4){cx, cy, cz, 0.f};
                    f32x4 c = (f32x4){cx, cy, cz, 1.0f};
                    if (u == 0) pb0 = c; else if (u == 1) pb1 = c;
                    else if (u == 2) pb2 = c; else pb3 = c;
                }
                f32x2 ncx = (f32x2){-cx, -cx};
                f32x2 ncy = (f32x2){-cy, -cy};
                f32x2 ncz = (f32x2){-cz, -cz};
                float bestd = -1.0f; int besti = 0;
#pragma unroll
                for (int j = 0; j < FT/2; ++j){
                    f32x2 d2;
                    {
#pragma clang fp contract(off)
                        f32x2 dx = px2[j] + ncx;       // pk_add; == px - cx bit-exact
                        f32x2 dy = py2[j] + ncy;
                        f32x2 dz = pz2[j] + ncz;
                        f32x2 xx = dx*dx, yy = dy*dy, zz = dz*dz;   // pk_mul
                        d2 = (xx + yy) + zz;                        // pk_add x2
                    }
                    f32x2 nd;
                    nd.x = fminf(pd2[j].x, d2.x);
                    nd.y = fminf(pd2[j].y, d2.y);
                    pd2[j] = nd;
                    if (nd.x > bestd){ bestd = nd.x; besti = t*FT + 2*j; }
                    if (nd.y > bestd){ bestd = nd.y; besti = t*FT + 2*j + 1; }
                }
                unsigned long long key =
                    (((unsigned long long)__float_as_uint(bestd)) << 32) |
                    (unsigned long long)(~(unsigned)besti);
                DPPMAX64(key, 0x111, 0xf);   // row_shr:1
                DPPMAX64(key, 0x112, 0xf);   // row_shr:2
                DPPMAX64(key, 0x114, 0xf);   // row_shr:4
                DPPMAX64(key, 0x118, 0xf);   // row_shr:8
                DPPMAX64(key, 0x142, 0xa);   // row_bcast:15 -> rows 1,3
                DPPMAX64(key, 0x143, 0xc);   // row_bcast:31 -> rows 2,3
                int p = s & 1;
                if (lane == 63) sh.f.cand[p][wave] = key;
                __syncthreads();
                ulonglong2 c01 = *reinterpret_cast<const ulonglong2*>(&sh.f.cand[p][0]);
                ulonglong2 c23 = *reinterpret_cast<const ulonglong2*>(&sh.f.cand[p][2]);
                unsigned long long m01 = (c01.x > c01.y) ? c01.x : c01.y;
                unsigned long long m23 = (c23.x > c23.y) ? c23.x : c23.y;
                unsigned long long km  = (m01 > m23) ? m01 : m23;
                cur = (int)(~(uint32_t)km);
            }
        }
        if (t == 0)   // trailing group (cells NS-4..NS-1)
            publish_cent4(cent, b*NS + (NS - 4), pb0, pb1, pb2, pb3);
        __syncthreads();
        for (int i = t; i < NS; i += 256){
            f32x4 c = sh.f.SC[i];
            float* o = out_newxyz + ((size_t)b*NS + i)*3;
            o[0] = c[0]; o[1] = c[1]; o[2] = c[2];
        }
    } else {
        // ------------------------------------------------ worker: qball + layer0 for 2 cells
        // s-major ordering: worker w covers cells (b, 2*stile), (b, 2*stile+1)
        // with stile = w>>3, b = w&7 -> dispatch order == availability order.
        const int w = (int)blockIdx.x - NB;
        const int stile = w >> 3;
        const int b = w & 7;
        const int wave = t >> 6, lane = t & 63;
        const int q = lane >> 4, l16 = lane & 15;

        // prefetch weight fragments while fps produces our centroids
        bf16x8 Bf[4][3];
#pragma unroll
        for (int nt = 0; nt < 4; ++nt)
#pragma unroll
            for (int s = 0; s < 3; ++s)
                Bf[nt][s] = load_bf8(w0b + (nt*16 + l16)*96 + s*32 + q*8);

        if (t == 0){
            sh.w.Lc[0] = wait_cent(cent, b*NS + stile*2 + 0);
            sh.w.Lc[1] = wait_cent(cent, b*NS + stile*2 + 1);
        }
        __syncthreads();

        // qball: wave 0 -> cell0, wave 1 -> cell1 (verbatim scan, idx into LDS)
        if (wave < 2){
            f32x4 qc = sh.w.Lc[wave];
            float qx = qc[0], qy = qc[1], qz = qc[2];
            float qn = qx*qx;
            qn = fmaf(qy, qy, qn);
            qn = fmaf(qz, qz, qn);
            const float* base = xyz + (size_t)b * (NPTS*3);
            int cnt = 0, first = 0;
            for (int c0 = 0; c0 < NPTS; c0 += 64){
                int i = c0 + lane;
                float x = base[i*3+0], y = base[i*3+1], z = base[i*3+2];
                float xn = x*x;
                xn = fmaf(y, y, xn);
                xn = fmaf(z, z, xn);
                float dot = qx*x;
                dot = fmaf(qy, y, dot);
                dot = fmaf(qz, z, dot);
                float d;
                {
#pragma clang fp contract(off)
                    d = -2.0f * dot;
                    d = d + qn;
                    d = d + xn;
                }
                bool in = !(d > R2);
                unsigned long long m = __ballot(in);
                if (in){
                    int rank = __popcll(m & ((1ull << lane) - 1ull));
                    int pos = cnt + rank;
                    if (pos < NK) sh.w.idxL[wave][pos] = i;
                }
                if (cnt == 0 && m) first = c0 + (__ffsll((unsigned long long)m) - 1);
                cnt += __popcll(m);
                if (cnt >= NK) break;
            }
            if (cnt < NK){
                for (int p = cnt + lane; p < NK; p += 64) sh.w.idxL[wave][p] = first;
            }
        }
        __syncthreads();

        // layer0 body (identical math to the old layer0_mfma block)
        const int rowbase = (b*NS + stile*2)*NK;      // rows [rowbase, rowbase+64)
        const int r0 = rowbase + wave*16;
        const int cell = wave >> 1;
        const int sample = (wave & 1)*16 + l16;
        const int id = sh.w.idxL[cell][sample];
        const float* prow = pts + (((size_t)b << 12) + id)*64;
        const float* xr   = xyz + (((size_t)b << 12) + id)*3;
        f32x4 qc = sh.w.Lc[cell];
        float d0 = xr[0]-qc[0], d1 = xr[1]-qc[1], d2 = xr[2]-qc[2];

        f32x4 acc[4];
#pragma unroll
        for (int nt = 0; nt < 4; ++nt) acc[nt] = (f32x4){0.f,0.f,0.f,0.f};

#pragma unroll
        for (int s = 0; s < 3; ++s){
            const int k0 = s*32 + q*8;
            bf16x8 a;
#pragma unroll
            for (int j = 0; j < 8; ++j){
                int k = k0 + j;
                float v = (k < 3) ? ((k == 0) ? d0 : ((k == 1) ? d1 : d2))
                                  : ((k < 67) ? prow[k-3] : 0.f);
                a[j] = (short)f2bf(v);
            }
#pragma unroll
            for (int nt = 0; nt < 4; ++nt)
                acc[nt] = __builtin_amdgcn_mfma_f32_16x16x32_bf16(a, Bf[nt][s], acc[nt], 0, 0, 0);
        }
        // C/D: col=lane&15, row=quad*4+reg. Epilogue: bias, store, f32 stats partials.
#pragma unroll
        for (int nt = 0; nt < 4; ++nt){
            int c = nt*16 + l16;
            float bb = b0[c];
            float sps = 0.f, spq = 0.f;
#pragma unroll
            for (int reg = 0; reg < 4; ++reg){
                int rr = r0 + q*4 + reg;
                float h = acc[nt][reg] + bb;
                sps += h;
                spq = fmaf(h, h, spq);
                z0[(size_t)rr*64 + c] = f2bf(h);
            }
            sh.w.S_s[wave*4 + q][c] = sps;
            sh.w.S_q[wave*4 + q][c] = spq;
        }
        __syncthreads();
        if (t < 64){
            double ss = 0.0, sq = 0.0;
#pragma unroll
            for (int i = 0; i < 16; ++i){ ss += (double)sh.w.S_s[i][t]; sq += (double)sh.w.S_q[i][t]; }
            int cp = blockIdx.x & (NCOPY-1);
            atomicAdd(&accumOut[cp*256 + t], ss);
            atomicAdd(&accumOut[cp*256 + 128 + t], sq);
        }
    }
}

// ---------------------------------------------------------------- weight prep (fp32 -> bf16) + accum zeroing + cent flag clear
__global__ void prep_kernel(const float* __restrict__ w0, const float* __restrict__ w1,
                            const float* __restrict__ w2, uint16_t* __restrict__ w0b,
                            uint16_t* __restrict__ w1b, uint16_t* __restrict__ w2b,
                            double* __restrict__ accumAll, float* __restrict__ cent){
    int t = blockIdx.x*256 + threadIdx.x;
    int stride = gridDim.x*256;
    for (int i = t; i < 3*NCOPY*256; i += stride) accumAll[i] = 0.0;
    // clear centroid mailboxes (flag word must be 0 before mega workers poll;
    // kernel-boundary L2 writeback publishes these zeros to the coherent point)
    for (int i = t; i < NB*NS; i += stride)
        ((f32x4*)cent)[i] = (f32x4){0.f, 0.f, 0.f, 0.f};
    for (int i = t; i < 64*96; i += stride){
        int n = i/96, c = i%96;
        w0b[i] = (c < 67) ? f2bf(w0[n*67 + c]) : (uint16_t)0;
    }
    for (int i = t; i < 64*64; i += stride)  w1b[i] = f2bf(w1[i]);
    for (int i = t; i < 128*64; i += stride) w2b[i] = f2bf(w2[i]);
}

// ---------------------------------------------------------------- layer 1: inline BN-param + BN+relu+GEMM K=64 + fused stats
// TPB=4 row-tiles per block (grid 1024): amortizes the NCOPY double-reduce
// preamble and weight/param loads 4x, and collapses stats atomics 4x
// (register-carried double partials, one atomicAdd at the end). NO fences.
__global__ __launch_bounds__(256) void layer1_mfma(const uint16_t* __restrict__ zin,
                                                   const double* __restrict__ accumIn,
                                                   const float* __restrict__ g,
                                                   const float* __restrict__ be,
                                                   const uint16_t* __restrict__ wb,
                                                   const float* __restrict__ bias,
                                                   uint16_t* __restrict__ zout,
                                                   double* __restrict__ accumOut){
    constexpr int NT = 4;
    constexpr int TPB = 4;
    __shared__ float sc_l[64], sh_l[64];
    __shared__ float S_s[16][64], S_q[16][64];
    const int t = threadIdx.x;
    if (t < 64){
        double s = 0.0, qq = 0.0;
#pragma unroll
        for (int cp = 0; cp < NCOPY; ++cp){
            s  += accumIn[cp*256 + t];
            qq += accumIn[cp*256 + 128 + t];
        }
        double mean = s / (double)NROWS;
        double var  = qq / (double)NROWS - mean*mean;
        double rs = 1.0 / sqrt(var + 1e-5);
        double scv = (double)g[t] * rs;
        sc_l[t] = (float)scv;
        sh_l[t] = (float)((double)be[t] - mean*scv);
    }
    __syncthreads();

    const int wave = t >> 6, lane = t & 63;
    const int q = lane >> 4, l16 = lane & 15;

    bf16x8 Bf[NT][2];
#pragma unroll
    for (int nt = 0; nt < NT; ++nt)
#pragma unroll
        for (int s = 0; s < 2; ++s)
            Bf[nt][s] = load_bf8(wb + (nt*16 + l16)*64 + s*32 + q*8);

    float sc[2][8], sh[2][8];
#pragma unroll
    for (int s = 0; s < 2; ++s)
#pragma unroll
        for (int j = 0; j < 8; ++j){
            sc[s][j] = sc_l[s*32 + q*8 + j];
            sh[s][j] = sh_l[s*32 + q*8 + j];
        }

    double accS = 0.0, accQ = 0.0;   // t<64 cross-tile stats partials

    for (int tile = 0; tile < TPB; ++tile){
        const int r0 = (blockIdx.x*TPB + tile)*64 + wave*16;

        f32x4 acc[NT];
#pragma unroll
        for (int nt = 0; nt < NT; ++nt) acc[nt] = (f32x4){0.f,0.f,0.f,0.f};

        const uint16_t* zr = zin + (size_t)(r0 + l16)*64;
#pragma unroll
        for (int s = 0; s < 2; ++s){
            uint4 u = *reinterpret_cast<const uint4*>(zr + s*32 + q*8);
            float h[8];
            h[0] = bf2f((uint16_t)(u.x & 0xFFFF)); h[1] = bf2f((uint16_t)(u.x >> 16));
            h[2] = bf2f((uint16_t)(u.y & 0xFFFF)); h[3] = bf2f((uint16_t)(u.y >> 16));
            h[4] = bf2f((uint16_t)(u.z & 0xFFFF)); h[5] = bf2f((uint16_t)(u.z >> 16));
            h[6] = bf2f((uint16_t)(u.w & 0xFFFF)); h[7] = bf2f((uint16_t)(u.w >> 16));
            bf16x8 a;
#pragma unroll
            for (int j = 0; j < 8; ++j){
                float v = fmaxf(fmaf(h[j], sc[s][j], sh[s][j]), 0.f);
                a[j] = (short)f2bf(v);
            }
#pragma unroll
            for (int nt = 0; nt < NT; ++nt)
                acc[nt] = __builtin_amdgcn_mfma_f32_16x16x32_bf16(a, Bf[nt][s], acc[nt], 0, 0, 0);
        }
#pragma unroll
        for (int nt = 0; nt < NT; ++nt){
            int c = nt*16 + l16;
            float bb = bias[c];
            float sps = 0.f, spq = 0.f;
#pragma unroll
            for (int reg = 0; reg < 4; ++reg){
                int rr = r0 + q*4 + reg;
                float h = acc[nt][reg] + bb;
                sps += h;
                spq = fmaf(h, h, spq);
                zout[(size_t)rr*64 + c] = f2bf(h);
            }
            S_s[wave*4 + q][c] = sps;
            S_q[wave*4 + q][c] = spq;
        }
        __syncthreads();
        if (t < 64){
#pragma unroll
            for (int i = 0; i < 16; ++i){ accS += (double)S_s[i][t]; accQ += (double)S_q[i][t]; }
        }
        __syncthreads();
    }
    if (t < 64){
        int cp = blockIdx.x & (NCOPY-1);
        atomicAdd(&accumOut[cp*256 + t], accS);
        atomicAdd(&accumOut[cp*256 + 128 + t], accQ);
    }
}

// ---------------------------------------------------------------- layer 2: BN+relu+GEMM K=64 -> 128 + fused stats + fused max/min POOLING
// TPB=4 tiles per block (grid 1024); per-tile pooling epilogue unchanged.
__global__ __launch_bounds__(256) void layer2_mfma(const uint16_t* __restrict__ zin,
                                                   const double* __restrict__ accumIn,
                                                   const float* __restrict__ g,
                                                   const float* __restrict__ be,
                                                   const uint16_t* __restrict__ wb,
                                                   const float* __restrict__ bias,
                                                   float2* __restrict__ pool,
                                                   double* __restrict__ accumOut){
    constexpr int NT = 8;
    constexpr int TPB = 4;
    __shared__ float sc_l[64], sh_l[64];
    __shared__ float S_s[16][128], S_q[16][128];
    __shared__ float P_mx[16][128], P_mn[16][128];
    const int t = threadIdx.x;
    if (t < 64){
        double s = 0.0, qq = 0.0;
#pragma unroll
        for (int cp = 0; cp < NCOPY; ++cp){
            s  += accumIn[cp*256 + t];
            qq += accumIn[cp*256 + 128 + t];
        }
        double mean = s / (double)NROWS;
        double var  = qq / (double)NROWS - mean*mean;
        double rs = 1.0 / sqrt(var + 1e-5);
        double scv = (double)g[t] * rs;
        sc_l[t] = (float)scv;
        sh_l[t] = (float)((double)be[t] - mean*scv);
    }
    __syncthreads();

    const int wave = t >> 6, lane = t & 63;
    const int q = lane >> 4, l16 = lane & 15;

    bf16x8 Bf[NT][2];
#pragma unroll
    for (int nt = 0; nt < NT; ++nt)
#pragma unroll
        for (int s = 0; s < 2; ++s)
            Bf[nt][s] = load_bf8(wb + (nt*16 + l16)*64 + s*32 + q*8);

    float sc[2][8], sh[2][8];
#pragma unroll
    for (int s = 0; s < 2; ++s)
#pragma unroll
        for (int j = 0; j < 8; ++j){
            sc[s][j] = sc_l[s*32 + q*8 + j];
            sh[s][j] = sh_l[s*32 + q*8 + j];
        }

    double accS = 0.0, accQ = 0.0;   // t<128 cross-tile stats partials

    for (int tile = 0; tile < TPB; ++tile){
        const int r0 = (blockIdx.x*TPB + tile)*64 + wave*16;

        f32x4 acc[NT];
#pragma unroll
        for (int nt = 0; nt < NT; ++nt) acc[nt] = (f32x4){0.f,0.f,0.f,0.f};

        const uint16_t* zr = zin + (size_t)(r0 + l16)*64;
#pragma unroll
        for (int s = 0; s < 2; ++s){
            uint4 u = *reinterpret_cast<const uint4*>(zr + s*32 + q*8);
            float h[8];
            h[0] = bf2f((uint16_t)(u.x & 0xFFFF)); h[1] = bf2f((uint16_t)(u.x >> 16));
            h[2] = bf2f((uint16_t)(u.y & 0xFFFF)); h[3] = bf2f((uint16_t)(u.y >> 16));
            h[4] = bf2f((uint16_t)(u.z & 0xFFFF)); h[5] = bf2f((uint16_t)(u.z >> 16));
            h[6] = bf2f((uint16_t)(u.w & 0xFFFF)); h[7] = bf2f((uint16_t)(u.w >> 16));
            bf16x8 a;
#pragma unroll
            for (int j = 0; j < 8; ++j){
                float v = fmaxf(fmaf(h[j], sc[s][j], sh[s][j]), 0.f);
                a[j] = (short)f2bf(v);
            }
#pragma unroll
            for (int nt = 0; nt < NT; ++nt)
                acc[nt] = __builtin_amdgcn_mfma_f32_16x16x32_bf16(a, Bf[nt][s], acc[nt], 0, 0, 0);
        }
#pragma unroll
        for (int nt = 0; nt < NT; ++nt){
            int c = nt*16 + l16;
            float bb = bias[c];
            float sps = 0.f, spq = 0.f;
            float mx = -1e30f, mn = 1e30f;
#pragma unroll
            for (int reg = 0; reg < 4; ++reg){
                float h = acc[nt][reg] + bb;
                sps += h;
                spq = fmaf(h, h, spq);
                mx = fmaxf(mx, h);
                mn = fminf(mn, h);
            }
            S_s[wave*4 + q][c] = sps;
            S_q[wave*4 + q][c] = spq;
            P_mx[wave*4 + q][c] = mx;
            P_mn[wave*4 + q][c] = mn;
        }
        __syncthreads();
        if (t < 128){
#pragma unroll
            for (int i = 0; i < 16; ++i){ accS += (double)S_s[i][t]; accQ += (double)S_q[i][t]; }
        }
        // pooling: each tile covers 2 groups of 32 rows (= 2 (b,s) cells)
        {
            int gidx = t >> 7;          // 0..1
            int c = t & 127;
            float mx = -1e30f, mn = 1e30f;
#pragma unroll
            for (int i = 0; i < 8; ++i){
                mx = fmaxf(mx, P_mx[gidx*8 + i][c]);
                mn = fminf(mn, P_mn[gidx*8 + i][c]);
            }
            pool[(size_t)((blockIdx.x*TPB + tile)*2 + gidx)*128 + c] = make_float2(mx, mn);
        }
        __syncthreads();
    }
    if (t < 128){
        int cp = blockIdx.x & (NCOPY-1);
        atomicAdd(&accumOut[cp*256 + t], accS);
        atomicAdd(&accumOut[cp*256 + 128 + t], accQ);
    }
}

// ---------------------------------------------------------------- final: inline BN-param + select max/min by sign(scale) + BN + relu + transpose
// Grid 1024, 4 chunks per block: amortizes the preamble 4x.
__global__ __launch_bounds__(256) void final_kernel(const float2* __restrict__ pool,
                                                    const double* __restrict__ accumIn,
                                                    const float* __restrict__ g,
                                                    const float* __restrict__ be,
                                                    float* __restrict__ out){
    __shared__ float sc_l[128], sh_l[128];
    const int t0 = threadIdx.x;
    if (t0 < 128){
        double s = 0.0, qq = 0.0;
#pragma unroll
        for (int cp = 0; cp < NCOPY; ++cp){
            s  += accumIn[cp*256 + t0];
            qq += accumIn[cp*256 + 128 + t0];
        }
        double mean = s / (double)NROWS;
        double var  = qq / (double)NROWS - mean*mean;
        double rs = 1.0 / sqrt(var + 1e-5);
        double scv = (double)g[t0] * rs;
        sc_l[t0] = (float)scv;
        sh_l[t0] = (float)((double)be[t0] - mean*scv);
    }
    __syncthreads();

#pragma unroll
    for (int it = 0; it < 4; ++it){
        int t = blockIdx.x*1024 + it*256 + threadIdx.x;   // 1048576 == pool linear index
        int o = t & 127;
        int s = (t >> 7) & 1023;
        int b = t >> 17;
        float2 p = pool[t];
        float sc = sc_l[o], sh = sh_l[o];
        float zsel = (sc >= 0.f) ? p.x : p.y;
        float y = fmaxf(fmaf(zsel, sc, sh), 0.f);
        out[24576 + ((size_t)b << 17) + ((size_t)o << 10) + s] = y;
    }
}

// ---------------------------------------------------------------- launch
extern "C" void kernel_launch(void* const* d_in, const int* in_sizes, int n_in,
                              void* d_out, int out_size, void* d_ws, size_t ws_size,
                              hipStream_t stream) {
    const float* xyz = (const float*)d_in[0];
    const float* pts = (const float*)d_in[1];
    const float* w0  = (const float*)d_in[2];
    const float* b0  = (const float*)d_in[3];
    const float* g0  = (const float*)d_in[4];
    const float* be0 = (const float*)d_in[5];
    const float* w1  = (const float*)d_in[6];
    const float* b1  = (const float*)d_in[7];
    const float* g1  = (const float*)d_in[8];
    const float* be1 = (const float*)d_in[9];
    const float* w2  = (const float*)d_in[10];
    const float* b2  = (const float*)d_in[11];
    const float* g2  = (const float*)d_in[12];
    const float* be2 = (const float*)d_in[13];
    float* out = (float*)d_out;

    char* ws = (char*)d_ws;
    // accum: 3 layers x NCOPY x 256 doubles = 196608 B
    double*   accum0 = (double*)(ws + 0);
    double*   accum1 = (double*)(ws + 65536);
    double*   accum2 = (double*)(ws + 131072);
    uint16_t* w0b    = (uint16_t*)(ws + 196608);    // 12288 B
    uint16_t* w1b    = (uint16_t*)(ws + 208896);    // 8192 B
    uint16_t* w2b    = (uint16_t*)(ws + 217088);    // 16384 B
    uint16_t* z0     = (uint16_t*)(ws + 262144);    // 33554432 B
    uint16_t* z1     = (uint16_t*)(ws + 33816576);  // 33554432 B
    float2*   pool   = (float2*)  (ws + 67371008);  // 8388608 B
    float*    cent   = (float*)   (ws + 75759616);  // 131072 B centroid mailboxes

    prep_kernel<<<32, 256, 0, stream>>>(w0, w1, w2, w0b, w1b, w2b, accum0, cent);
    // mega: blocks 0..7 = fps producers; blocks 8..4103 = qball+layer0 workers
    // overlapped under the fps serial shadow.
    mega_kernel<<<NB + 4096, 256, 0, stream>>>(xyz, pts, w0b, b0, z0, accum0, cent, out);
    layer1_mfma<<<1024, 256, 0, stream>>>(z0, accum0, g0, be0, w1b, b1, z1, accum1);
    layer2_mfma<<<1024, 256, 0, stream>>>(z1, accum1, g1, be1, w2b, b2, pool, accum2);
    final_kernel<<<1024, 256, 0, stream>>>(pool, accum2, g2, be2, out);
}

// Round 5
// 756.615 us; speedup vs baseline: 2.2818x; 1.0157x over previous
//
#include <hip/hip_runtime.h>
#include <stdint.h>

#define NB 8
#define NPTS 4096
#define NS 1024
#define NK 32
#define NROWS (NB*NS*NK)   // 262144
#define R2 0.04f
#define NCOPY 8            // atomic spreading copies for stats accum (r5: 32->8, cuts preamble reads 4x)

typedef __attribute__((ext_vector_type(8))) short bf16x8;   // 8 bf16 in 4 VGPRs
typedef __attribute__((ext_vector_type(4))) float f32x4;    // MFMA 16x16 accumulator
typedef __attribute__((ext_vector_type(2))) float f32x2;    // packed fp32 (v_pk_*)

__device__ __forceinline__ float bf2f(uint16_t u){
    uint32_t v = ((uint32_t)u) << 16;
    return __uint_as_float(v);
}
__device__ __forceinline__ uint16_t f2bf(float f){
    uint32_t u = __float_as_uint(f);
    uint32_t r = (u + 0x7FFFu + ((u >> 16) & 1u)) >> 16;
    return (uint16_t)r;
}
__device__ __forceinline__ bf16x8 load_bf8(const uint16_t* p){
    return *reinterpret_cast<const bf16x8*>(p);
}

// SESSION LESSONS (measured):
//  - R2: per-block device-scope fences / acq_rel atomics are POISON on gfx950
//    (L2 wb/inv storm, +900us over 8k blocks). Plain atomicAdd is fine.
//  - R3: BAR_LGKM (inline-asm lgkm-only barrier) + wave-split publish REGRESSED
//    mega 635->668 vs plain __syncthreads + t0-publish. Keep __syncthreads.
//  - R4: batched publish-per-4 == per-iter publish == 634us. The +52us vs
//    standalone fps (583) is LOAD-DEPENDENT CLOCK DROOP (~2.2 vs 2.4 GHz),
//    not store-drain. Mega is at its structural floor; don't re-attack.
//  - R3/R5: TPB tile amortization + register-carried stats in layer1/2/final.

// ---------------------------------------------------------------- producer/consumer plumbing
// Batched centroid publish: 4 cells per group, each cell ONE 16B L2-bypass
// store {x,y,z,flag=1.0f}. sc0+sc1 makes stores visible at the coherent point
// past the non-coherent per-XCD L2s. Flag travels in the same 16B transaction
// as its coords -> workers poll per-cell flags, no inter-store ordering needed.
__device__ __forceinline__ void publish_cent4(float* cent, int cell0,
                                              f32x4 c0, f32x4 c1, f32x4 c2, f32x4 c3){
    unsigned long long a = (unsigned long long)(uintptr_t)(cent + (size_t)cell0*4);
    asm volatile("global_store_dwordx4 %0, %1, off sc0 sc1\n\t"
                 "global_store_dwordx4 %0, %2, off offset:16 sc0 sc1\n\t"
                 "global_store_dwordx4 %0, %3, off offset:32 sc0 sc1\n\t"
                 "global_store_dwordx4 %0, %4, off offset:48 sc0 sc1"
                 :: "v"(a), "v"(c0), "v"(c1), "v"(c2), "v"(c3)
                 : "memory");
}
// Consumer: poll the flag word with an agent-scope relaxed load (bypasses stale
// L2), s_sleep between polls; once set, re-read the full 16B with a bypass load.
__device__ __forceinline__ f32x4 wait_cent(const float* cent, int cell){
    const uint32_t* wp = (const uint32_t*)(cent + (size_t)cell*4) + 3;
    while (__hip_atomic_load(wp, __ATOMIC_RELAXED, __HIP_MEMORY_SCOPE_AGENT)
           != 0x3F800000u)
        __builtin_amdgcn_s_sleep(64);
    f32x4 r;
    unsigned long long a = (unsigned long long)(uintptr_t)(cent + (size_t)cell*4);
    asm volatile("global_load_dwordx4 %0, %1, off sc0 sc1\n\ts_waitcnt vmcnt(0)"
                 : "=v"(r) : "v"(a) : "memory");
    return r;
}

// 64-bit max with a DPP-moved partner; masked-off / invalid lanes receive 0,
// which never wins (low word of a real key is ~idx >= 0xFFFFF000 != 0).
#define DPPMAX64(key, ctrl, rmask)                                             \
    {                                                                          \
        uint32_t _lo = (uint32_t)(key), _hi = (uint32_t)((key) >> 32);         \
        uint32_t _olo = (uint32_t)__builtin_amdgcn_update_dpp(                 \
            0, (int)_lo, (ctrl), (rmask), 0xf, true);                          \
        uint32_t _ohi = (uint32_t)__builtin_amdgcn_update_dpp(                 \
            0, (int)_hi, (ctrl), (rmask), 0xf, true);                          \
        unsigned long long _o = (((unsigned long long)_ohi) << 32) | _olo;     \
        key = (_o > (key)) ? _o : (key);                                       \
    }

// ---------------------------------------------------------------- mega-kernel shared union
// One static LDS union sized >80KB forces 1 block/CU for EVERY block of the
// mega-kernel -> fps blocks own their CU exclusively.
struct FpsSh {
    float LX[NPTS], LY[NPTS], LZ[NPTS];
    f32x4 SC[NS];
    alignas(16) unsigned long long cand[2][4];
};
struct WrkSh {
    float S_s[16][64], S_q[16][64];
    int   idxL[2][NK];
    f32x4 Lc[2];
};
union MegaSh { FpsSh f; WrkSh w; char force_one_block_per_cu[86016]; };

// ---------------------------------------------------------------- mega: fps (blocks 0..7) + qball/layer0 workers (blocks 8..4103)
// fps r10 loop VERBATIM (r1-session structure: __syncthreads barrier, t==0 does
// SC write; publish batched per-4 at group top).
// Serial floor: 1024 dependent argmax iters x ~1360cyc at the LOADED clock.
// Proven-regression list (do not retry): coord-carry cand (r5), float4 LDS
// coords (r8), 512 threads (r9), ballot owner-find / equality-mask argmax
// (r5, r11), helper-block fusion of prep/ptsconv (r12/r13), per-block
// device-scope fence/ticket tails (R2: +900us), BAR_LGKM + wave-split (R3: +33us).
// Proven wins: DPP-VALU u64 reduce (r3), pk-f32 distance (r10).
// DO NOT TOUCH the distance math: contract(off), a+(-c) == a-c IEEE —
// selection is bit-exact vs reference (verified r2-r13).
#define FT 16
__global__ __launch_bounds__(256) void mega_kernel(const float* __restrict__ xyz,
                                                   const float* __restrict__ pts,
                                                   const uint16_t* __restrict__ w0b,
                                                   const float* __restrict__ b0,
                                                   uint16_t* __restrict__ z0,
                                                   double* __restrict__ accumOut,
                                                   float* __restrict__ cent,
                                                   float* __restrict__ out_newxyz){
    __shared__ MegaSh sh;
    const int t = threadIdx.x;

    if (blockIdx.x < NB){
        // ------------------------------------------------ fps producer (1 block = 1 batch)
        const int b = blockIdx.x;
        const float* base = xyz + (size_t)b * (NPTS*3);
        f32x2 px2[FT/2], py2[FT/2], pz2[FT/2], pd2[FT/2];
#pragma unroll
        for (int j = 0; j < FT/2; ++j){
            int i = t*FT + 2*j;
            float x0 = base[i*3+0], y0 = base[i*3+1], z0c = base[i*3+2];
            float x1 = base[i*3+3], y1 = base[i*3+4], z1c = base[i*3+5];
            px2[j] = (f32x2){x0, x1};
            py2[j] = (f32x2){y0, y1};
            pz2[j] = (f32x2){z0c, z1c};
            pd2[j] = (f32x2){1e10f, 1e10f};
            sh.f.LX[i]=x0; sh.f.LY[i]=y0; sh.f.LZ[i]=z0c;
            sh.f.LX[i+1]=x1; sh.f.LY[i+1]=y1; sh.f.LZ[i+1]=z1c;
        }
        __syncthreads();
        int cur = 0;
        const int wave = t >> 6, lane = t & 63;
        f32x4 pb0, pb1, pb2, pb3;    // previous group's centroids (lane 0 of wave 0)
        for (int s4 = 0; s4 < NS; s4 += 4){
            if (s4 && t == 0)
                publish_cent4(cent, b*NS + (s4 - 4), pb0, pb1, pb2, pb3);
#pragma unroll
            for (int u = 0; u < 4; ++u){
                const int s = s4 + u;
                float cx = sh.f.LX[cur], cy = sh.f.LY[cur], cz = sh.f.LZ[cur];
                if (t == 0){
                    sh.f.SC[s] = (f32x4){cx, cy, cz, 0.f};
                    f32x4 c = (f32x4){cx, cy, cz, 1.0f};
                    if (u == 0) pb0 = c; else if (u == 1) pb1 = c;
                    else if (u == 2) pb2 = c; else pb3 = c;
                }
                f32x2 ncx = (f32x2){-cx, -cx};
                f32x2 ncy = (f32x2){-cy, -cy};
                f32x2 ncz = (f32x2){-cz, -cz};
                float bestd = -1.0f; int besti = 0;
#pragma unroll
                for (int j = 0; j < FT/2; ++j){
                    f32x2 d2;
                    {
#pragma clang fp contract(off)
                        f32x2 dx = px2[j] + ncx;       // pk_add; == px - cx bit-exact
                        f32x2 dy = py2[j] + ncy;
                        f32x2 dz = pz2[j] + ncz;
                        f32x2 xx = dx*dx, yy = dy*dy, zz = dz*dz;   // pk_mul
                        d2 = (xx + yy) + zz;                        // pk_add x2
                    }
                    f32x2 nd;
                    nd.x = fminf(pd2[j].x, d2.x);
                    nd.y = fminf(pd2[j].y, d2.y);
                    pd2[j] = nd;
                    if (nd.x > bestd){ bestd = nd.x; besti = t*FT + 2*j; }
                    if (nd.y > bestd){ bestd = nd.y; besti = t*FT + 2*j + 1; }
                }
                unsigned long long key =
                    (((unsigned long long)__float_as_uint(bestd)) << 32) |
                    (unsigned long long)(~(unsigned)besti);
                DPPMAX64(key, 0x111, 0xf);   // row_shr:1
                DPPMAX64(key, 0x112, 0xf);   // row_shr:2
                DPPMAX64(key, 0x114, 0xf);   // row_shr:4
                DPPMAX64(key, 0x118, 0xf);   // row_shr:8
                DPPMAX64(key, 0x142, 0xa);   // row_bcast:15 -> rows 1,3
                DPPMAX64(key, 0x143, 0xc);   // row_bcast:31 -> rows 2,3
                int p = s & 1;
                if (lane == 63) sh.f.cand[p][wave] = key;
                __syncthreads();
                ulonglong2 c01 = *reinterpret_cast<const ulonglong2*>(&sh.f.cand[p][0]);
                ulonglong2 c23 = *reinterpret_cast<const ulonglong2*>(&sh.f.cand[p][2]);
                unsigned long long m01 = (c01.x > c01.y) ? c01.x : c01.y;
                unsigned long long m23 = (c23.x > c23.y) ? c23.x : c23.y;
                unsigned long long km  = (m01 > m23) ? m01 : m23;
                cur = (int)(~(uint32_t)km);
            }
        }
        if (t == 0)   // trailing group (cells NS-4..NS-1)
            publish_cent4(cent, b*NS + (NS - 4), pb0, pb1, pb2, pb3);
        __syncthreads();
        for (int i = t; i < NS; i += 256){
            f32x4 c = sh.f.SC[i];
            float* o = out_newxyz + ((size_t)b*NS + i)*3;
            o[0] = c[0]; o[1] = c[1]; o[2] = c[2];
        }
    } else {
        // ------------------------------------------------ worker: qball + layer0 for 2 cells
        // s-major ordering: worker w covers cells (b, 2*stile), (b, 2*stile+1)
        // with stile = w>>3, b = w&7 -> dispatch order == availability order.
        const int w = (int)blockIdx.x - NB;
        const int stile = w >> 3;
        const int b = w & 7;
        const int wave = t >> 6, lane = t & 63;
        const int q = lane >> 4, l16 = lane & 15;

        // prefetch weight fragments while fps produces our centroids
        bf16x8 Bf[4][3];
#pragma unroll
        for (int nt = 0; nt < 4; ++nt)
#pragma unroll
            for (int s = 0; s < 3; ++s)
                Bf[nt][s] = load_bf8(w0b + (nt*16 + l16)*96 + s*32 + q*8);

        if (t == 0){
            sh.w.Lc[0] = wait_cent(cent, b*NS + stile*2 + 0);
            sh.w.Lc[1] = wait_cent(cent, b*NS + stile*2 + 1);
        }
        __syncthreads();

        // qball: wave 0 -> cell0, wave 1 -> cell1 (verbatim scan, idx into LDS)
        if (wave < 2){
            f32x4 qc = sh.w.Lc[wave];
            float qx = qc[0], qy = qc[1], qz = qc[2];
            float qn = qx*qx;
            qn = fmaf(qy, qy, qn);
            qn = fmaf(qz, qz, qn);
            const float* base = xyz + (size_t)b * (NPTS*3);
            int cnt = 0, first = 0;
            for (int c0 = 0; c0 < NPTS; c0 += 64){
                int i = c0 + lane;
                float x = base[i*3+0], y = base[i*3+1], z = base[i*3+2];
                float xn = x*x;
                xn = fmaf(y, y, xn);
                xn = fmaf(z, z, xn);
                float dot = qx*x;
                dot = fmaf(qy, y, dot);
                dot = fmaf(qz, z, dot);
                float d;
                {
#pragma clang fp contract(off)
                    d = -2.0f * dot;
                    d = d + qn;
                    d = d + xn;
                }
                bool in = !(d > R2);
                unsigned long long m = __ballot(in);
                if (in){
                    int rank = __popcll(m & ((1ull << lane) - 1ull));
                    int pos = cnt + rank;
                    if (pos < NK) sh.w.idxL[wave][pos] = i;
                }
                if (cnt == 0 && m) first = c0 + (__ffsll((unsigned long long)m) - 1);
                cnt += __popcll(m);
                if (cnt >= NK) break;
            }
            if (cnt < NK){
                for (int p = cnt + lane; p < NK; p += 64) sh.w.idxL[wave][p] = first;
            }
        }
        __syncthreads();

        // layer0 body (identical math to the old layer0_mfma block)
        const int rowbase = (b*NS + stile*2)*NK;      // rows [rowbase, rowbase+64)
        const int r0 = rowbase + wave*16;
        const int cell = wave >> 1;
        const int sample = (wave & 1)*16 + l16;
        const int id = sh.w.idxL[cell][sample];
        const float* prow = pts + (((size_t)b << 12) + id)*64;
        const float* xr   = xyz + (((size_t)b << 12) + id)*3;
        f32x4 qc = sh.w.Lc[cell];
        float d0 = xr[0]-qc[0], d1 = xr[1]-qc[1], d2 = xr[2]-qc[2];

        f32x4 acc[4];
#pragma unroll
        for (int nt = 0; nt < 4; ++nt) acc[nt] = (f32x4){0.f,0.f,0.f,0.f};

#pragma unroll
        for (int s = 0; s < 3; ++s){
            const int k0 = s*32 + q*8;
            bf16x8 a;
#pragma unroll
            for (int j = 0; j < 8; ++j){
                int k = k0 + j;
                float v = (k < 3) ? ((k == 0) ? d0 : ((k == 1) ? d1 : d2))
                                  : ((k < 67) ? prow[k-3] : 0.f);
                a[j] = (short)f2bf(v);
            }
#pragma unroll
            for (int nt = 0; nt < 4; ++nt)
                acc[nt] = __builtin_amdgcn_mfma_f32_16x16x32_bf16(a, Bf[nt][s], acc[nt], 0, 0, 0);
        }
        // C/D: col=lane&15, row=quad*4+reg. Epilogue: bias, store, f32 stats partials.
#pragma unroll
        for (int nt = 0; nt < 4; ++nt){
            int c = nt*16 + l16;
            float bb = b0[c];
            float sps = 0.f, spq = 0.f;
#pragma unroll
            for (int reg = 0; reg < 4; ++reg){
                int rr = r0 + q*4 + reg;
                float h = acc[nt][reg] + bb;
                sps += h;
                spq = fmaf(h, h, spq);
                z0[(size_t)rr*64 + c] = f2bf(h);
            }
            sh.w.S_s[wave*4 + q][c] = sps;
            sh.w.S_q[wave*4 + q][c] = spq;
        }
        __syncthreads();
        if (t < 64){
            double ss = 0.0, sq = 0.0;
#pragma unroll
            for (int i = 0; i < 16; ++i){ ss += (double)sh.w.S_s[i][t]; sq += (double)sh.w.S_q[i][t]; }
            int cp = blockIdx.x & (NCOPY-1);
            atomicAdd(&accumOut[cp*256 + t], ss);
            atomicAdd(&accumOut[cp*256 + 128 + t], sq);
        }
    }
}

// ---------------------------------------------------------------- weight prep (fp32 -> bf16) + accum zeroing + cent flag clear
__global__ void prep_kernel(const float* __restrict__ w0, const float* __restrict__ w1,
                            const float* __restrict__ w2, uint16_t* __restrict__ w0b,
                            uint16_t* __restrict__ w1b, uint16_t* __restrict__ w2b,
                            double* __restrict__ accumAll, float* __restrict__ cent){
    int t = blockIdx.x*256 + threadIdx.x;
    int stride = gridDim.x*256;
    for (int i = t; i < 3*NCOPY*256; i += stride) accumAll[i] = 0.0;
    // clear centroid mailboxes (flag word must be 0 before mega workers poll;
    // kernel-boundary L2 writeback publishes these zeros to the coherent point)
    for (int i = t; i < NB*NS; i += stride)
        ((f32x4*)cent)[i] = (f32x4){0.f, 0.f, 0.f, 0.f};
    for (int i = t; i < 64*96; i += stride){
        int n = i/96, c = i%96;
        w0b[i] = (c < 67) ? f2bf(w0[n*67 + c]) : (uint16_t)0;
    }
    for (int i = t; i < 64*64; i += stride)  w1b[i] = f2bf(w1[i]);
    for (int i = t; i < 128*64; i += stride) w2b[i] = f2bf(w2[i]);
}

// ---------------------------------------------------------------- layer 1: inline BN-param + BN+relu+GEMM K=64 + fused stats
// TPB=8 row-tiles per block (grid 512): amortizes the NCOPY double-reduce
// preamble and weight/param loads 8x. Stats carried in per-thread float
// registers across ALL tiles -> NO barriers in the tile loop, ONE LDS
// exchange + ONE atomic round at the end.
__global__ __launch_bounds__(256) void layer1_mfma(const uint16_t* __restrict__ zin,
                                                   const double* __restrict__ accumIn,
                                                   const float* __restrict__ g,
                                                   const float* __restrict__ be,
                                                   const uint16_t* __restrict__ wb,
                                                   const float* __restrict__ bias,
                                                   uint16_t* __restrict__ zout,
                                                   double* __restrict__ accumOut){
    constexpr int NT = 4;
    constexpr int TPB = 8;
    __shared__ float sc_l[64], sh_l[64];
    __shared__ float S_s[16][64], S_q[16][64];
    const int t = threadIdx.x;
    if (t < 64){
        double s = 0.0, qq = 0.0;
#pragma unroll
        for (int cp = 0; cp < NCOPY; ++cp){
            s  += accumIn[cp*256 + t];
            qq += accumIn[cp*256 + 128 + t];
        }
        double mean = s / (double)NROWS;
        double var  = qq / (double)NROWS - mean*mean;
        double rs = 1.0 / sqrt(var + 1e-5);
        double scv = (double)g[t] * rs;
        sc_l[t] = (float)scv;
        sh_l[t] = (float)((double)be[t] - mean*scv);
    }
    __syncthreads();

    const int wave = t >> 6, lane = t & 63;
    const int q = lane >> 4, l16 = lane & 15;

    bf16x8 Bf[NT][2];
#pragma unroll
    for (int nt = 0; nt < NT; ++nt)
#pragma unroll
        for (int s = 0; s < 2; ++s)
            Bf[nt][s] = load_bf8(wb + (nt*16 + l16)*64 + s*32 + q*8);

    float sc[2][8], sh[2][8];
#pragma unroll
    for (int s = 0; s < 2; ++s)
#pragma unroll
        for (int j = 0; j < 8; ++j){
            sc[s][j] = sc_l[s*32 + q*8 + j];
            sh[s][j] = sh_l[s*32 + q*8 + j];
        }

    float statS[NT], statQ[NT];
#pragma unroll
    for (int nt = 0; nt < NT; ++nt){ statS[nt] = 0.f; statQ[nt] = 0.f; }
    float bb[NT];
#pragma unroll
    for (int nt = 0; nt < NT; ++nt) bb[nt] = bias[nt*16 + l16];

    for (int tile = 0; tile < TPB; ++tile){
        const int r0 = (blockIdx.x*TPB + tile)*64 + wave*16;

        f32x4 acc[NT];
#pragma unroll
        for (int nt = 0; nt < NT; ++nt) acc[nt] = (f32x4){0.f,0.f,0.f,0.f};

        const uint16_t* zr = zin + (size_t)(r0 + l16)*64;
#pragma unroll
        for (int s = 0; s < 2; ++s){
            uint4 u = *reinterpret_cast<const uint4*>(zr + s*32 + q*8);
            float h[8];
            h[0] = bf2f((uint16_t)(u.x & 0xFFFF)); h[1] = bf2f((uint16_t)(u.x >> 16));
            h[2] = bf2f((uint16_t)(u.y & 0xFFFF)); h[3] = bf2f((uint16_t)(u.y >> 16));
            h[4] = bf2f((uint16_t)(u.z & 0xFFFF)); h[5] = bf2f((uint16_t)(u.z >> 16));
            h[6] = bf2f((uint16_t)(u.w & 0xFFFF)); h[7] = bf2f((uint16_t)(u.w >> 16));
            bf16x8 a;
#pragma unroll
            for (int j = 0; j < 8; ++j){
                float v = fmaxf(fmaf(h[j], sc[s][j], sh[s][j]), 0.f);
                a[j] = (short)f2bf(v);
            }
#pragma unroll
            for (int nt = 0; nt < NT; ++nt)
                acc[nt] = __builtin_amdgcn_mfma_f32_16x16x32_bf16(a, Bf[nt][s], acc[nt], 0, 0, 0);
        }
#pragma unroll
        for (int nt = 0; nt < NT; ++nt){
            int c = nt*16 + l16;
#pragma unroll
            for (int reg = 0; reg < 4; ++reg){
                int rr = r0 + q*4 + reg;
                float h = acc[nt][reg] + bb[nt];
                statS[nt] += h;
                statQ[nt] = fmaf(h, h, statQ[nt]);
                zout[(size_t)rr*64 + c] = f2bf(h);
            }
        }
    }
    // one LDS stats exchange for the whole block
#pragma unroll
    for (int nt = 0; nt < NT; ++nt){
        int c = nt*16 + l16;
        S_s[wave*4 + q][c] = statS[nt];
        S_q[wave*4 + q][c] = statQ[nt];
    }
    __syncthreads();
    if (t < 64){
        double ss = 0.0, sq = 0.0;
#pragma unroll
        for (int i = 0; i < 16; ++i){ ss += (double)S_s[i][t]; sq += (double)S_q[i][t]; }
        int cp = blockIdx.x & (NCOPY-1);
        atomicAdd(&accumOut[cp*256 + t], ss);
        atomicAdd(&accumOut[cp*256 + 128 + t], sq);
    }
}

// ---------------------------------------------------------------- layer 2: BN+relu+GEMM K=64 -> 128 + fused stats + fused max/min POOLING
// TPB=8 tiles per block (grid 512); register-carried stats (one exchange at
// end); pooling keeps its 2 barriers/tile (P_mx/P_mn LDS reuse).
__global__ __launch_bounds__(256) void layer2_mfma(const uint16_t* __restrict__ zin,
                                                   const double* __restrict__ accumIn,
                                                   const float* __restrict__ g,
                                                   const float* __restrict__ be,
                                                   const uint16_t* __restrict__ wb,
                                                   const float* __restrict__ bias,
                                                   float2* __restrict__ pool,
                                                   double* __restrict__ accumOut){
    constexpr int NT = 8;
    constexpr int TPB = 8;
    __shared__ float sc_l[64], sh_l[64];
    __shared__ float S_s[16][128], S_q[16][128];
    __shared__ float P_mx[16][128], P_mn[16][128];
    const int t = threadIdx.x;
    if (t < 64){
        double s = 0.0, qq = 0.0;
#pragma unroll
        for (int cp = 0; cp < NCOPY; ++cp){
            s  += accumIn[cp*256 + t];
            qq += accumIn[cp*256 + 128 + t];
        }
        double mean = s / (double)NROWS;
        double var  = qq / (double)NROWS - mean*mean;
        double rs = 1.0 / sqrt(var + 1e-5);
        double scv = (double)g[t] * rs;
        sc_l[t] = (float)scv;
        sh_l[t] = (float)((double)be[t] - mean*scv);
    }
    __syncthreads();

    const int wave = t >> 6, lane = t & 63;
    const int q = lane >> 4, l16 = lane & 15;

    bf16x8 Bf[NT][2];
#pragma unroll
    for (int nt = 0; nt < NT; ++nt)
#pragma unroll
        for (int s = 0; s < 2; ++s)
            Bf[nt][s] = load_bf8(wb + (nt*16 + l16)*64 + s*32 + q*8);

    float sc[2][8], sh[2][8];
#pragma unroll
    for (int s = 0; s < 2; ++s)
#pragma unroll
        for (int j = 0; j < 8; ++j){
            sc[s][j] = sc_l[s*32 + q*8 + j];
            sh[s][j] = sh_l[s*32 + q*8 + j];
        }

    float statS[NT], statQ[NT];
#pragma unroll
    for (int nt = 0; nt < NT; ++nt){ statS[nt] = 0.f; statQ[nt] = 0.f; }
    float bb[NT];
#pragma unroll
    for (int nt = 0; nt < NT; ++nt) bb[nt] = bias[nt*16 + l16];

    for (int tile = 0; tile < TPB; ++tile){
        const int r0 = (blockIdx.x*TPB + tile)*64 + wave*16;

        f32x4 acc[NT];
#pragma unroll
        for (int nt = 0; nt < NT; ++nt) acc[nt] = (f32x4){0.f,0.f,0.f,0.f};

        const uint16_t* zr = zin + (size_t)(r0 + l16)*64;
#pragma unroll
        for (int s = 0; s < 2; ++s){
            uint4 u = *reinterpret_cast<const uint4*>(zr + s*32 + q*8);
            float h[8];
            h[0] = bf2f((uint16_t)(u.x & 0xFFFF)); h[1] = bf2f((uint16_t)(u.x >> 16));
            h[2] = bf2f((uint16_t)(u.y & 0xFFFF)); h[3] = bf2f((uint16_t)(u.y >> 16));
            h[4] = bf2f((uint16_t)(u.z & 0xFFFF)); h[5] = bf2f((uint16_t)(u.z >> 16));
            h[6] = bf2f((uint16_t)(u.w & 0xFFFF)); h[7] = bf2f((uint16_t)(u.w >> 16));
            bf16x8 a;
#pragma unroll
            for (int j = 0; j < 8; ++j){
                float v = fmaxf(fmaf(h[j], sc[s][j], sh[s][j]), 0.f);
                a[j] = (short)f2bf(v);
            }
#pragma unroll
            for (int nt = 0; nt < NT; ++nt)
                acc[nt] = __builtin_amdgcn_mfma_f32_16x16x32_bf16(a, Bf[nt][s], acc[nt], 0, 0, 0);
        }
#pragma unroll
        for (int nt = 0; nt < NT; ++nt){
            int c = nt*16 + l16;
            float mx = -1e30f, mn = 1e30f;
#pragma unroll
            for (int reg = 0; reg < 4; ++reg){
                float h = acc[nt][reg] + bb[nt];
                statS[nt] += h;
                statQ[nt] = fmaf(h, h, statQ[nt]);
                mx = fmaxf(mx, h);
                mn = fminf(mn, h);
            }
            P_mx[wave*4 + q][c] = mx;
            P_mn[wave*4 + q][c] = mn;
        }
        __syncthreads();
        // pooling: each tile covers 2 groups of 32 rows (= 2 (b,s) cells)
        {
            int gidx = t >> 7;          // 0..1
            int c = t & 127;
            float mx = -1e30f, mn = 1e30f;
#pragma unroll
            for (int i = 0; i < 8; ++i){
                mx = fmaxf(mx, P_mx[gidx*8 + i][c]);
                mn = fminf(mn, P_mn[gidx*8 + i][c]);
            }
            pool[(size_t)((blockIdx.x*TPB + tile)*2 + gidx)*128 + c] = make_float2(mx, mn);
        }
        __syncthreads();
    }
    // one LDS stats exchange for the whole block
#pragma unroll
    for (int nt = 0; nt < NT; ++nt){
        int c = nt*16 + l16;
        S_s[wave*4 + q][c] = statS[nt];
        S_q[wave*4 + q][c] = statQ[nt];
    }
    __syncthreads();
    if (t < 128){
        double ss = 0.0, sq = 0.0;
#pragma unroll
        for (int i = 0; i < 16; ++i){ ss += (double)S_s[i][t]; sq += (double)S_q[i][t]; }
        int cp = blockIdx.x & (NCOPY-1);
        atomicAdd(&accumOut[cp*256 + t], ss);
        atomicAdd(&accumOut[cp*256 + 128 + t], sq);
    }
}

// ---------------------------------------------------------------- final: inline BN-param + select max/min by sign(scale) + BN + relu + transpose
// Grid 512, 8 chunks per block: amortizes the preamble 8x.
__global__ __launch_bounds__(256) void final_kernel(const float2* __restrict__ pool,
                                                    const double* __restrict__ accumIn,
                                                    const float* __restrict__ g,
                                                    const float* __restrict__ be,
                                                    float* __restrict__ out){
    __shared__ float sc_l[128], sh_l[128];
    const int t0 = threadIdx.x;
    if (t0 < 128){
        double s = 0.0, qq = 0.0;
#pragma unroll
        for (int cp = 0; cp < NCOPY; ++cp){
            s  += accumIn[cp*256 + t0];
            qq += accumIn[cp*256 + 128 + t0];
        }
        double mean = s / (double)NROWS;
        double var  = qq / (double)NROWS - mean*mean;
        double rs = 1.0 / sqrt(var + 1e-5);
        double scv = (double)g[t0] * rs;
        sc_l[t0] = (float)scv;
        sh_l[t0] = (float)((double)be[t0] - mean*scv);
    }
    __syncthreads();

#pragma unroll
    for (int it = 0; it < 8; ++it){
        int t = blockIdx.x*2048 + it*256 + threadIdx.x;   // 1048576 == pool linear index
        int o = t & 127;
        int s = (t >> 7) & 1023;
        int b = t >> 17;
        float2 p = pool[t];
        float sc = sc_l[o], sh = sh_l[o];
        float zsel = (sc >= 0.f) ? p.x : p.y;
        float y = fmaxf(fmaf(zsel, sc, sh), 0.f);
        out[24576 + ((size_t)b << 17) + ((size_t)o << 10) + s] = y;
    }
}

// ---------------------------------------------------------------- launch
extern "C" void kernel_launch(void* const* d_in, const int* in_sizes, int n_in,
                              void* d_out, int out_size, void* d_ws, size_t ws_size,
                              hipStream_t stream) {
    const float* xyz = (const float*)d_in[0];
    const float* pts = (const float*)d_in[1];
    const float* w0  = (const float*)d_in[2];
    const float* b0  = (const float*)d_in[3];
    const float* g0  = (const float*)d_in[4];
    const float* be0 = (const float*)d_in[5];
    const float* w1  = (const float*)d_in[6];
    const float* b1  = (const float*)d_in[7];
    const float* g1  = (const float*)d_in[8];
    const float* be1 = (const float*)d_in[9];
    const float* w2  = (const float*)d_in[10];
    const float* b2  = (const float*)d_in[11];
    const float* g2  = (const float*)d_in[12];
    const float* be2 = (const float*)d_in[13];
    float* out = (float*)d_out;

    char* ws = (char*)d_ws;
    // accum: 3 layers x NCOPY x 256 doubles = 49152 B (NCOPY=8)
    double*   accum0 = (double*)(ws + 0);
    double*   accum1 = (double*)(ws + 65536);
    double*   accum2 = (double*)(ws + 131072);
    uint16_t* w0b    = (uint16_t*)(ws + 196608);    // 12288 B
    uint16_t* w1b    = (uint16_t*)(ws + 208896);    // 8192 B
    uint16_t* w2b    = (uint16_t*)(ws + 217088);    // 16384 B
    uint16_t* z0     = (uint16_t*)(ws + 262144);    // 33554432 B
    uint16_t* z1     = (uint16_t*)(ws + 33816576);  // 33554432 B
    float2*   pool   = (float2*)  (ws + 67371008);  // 8388608 B
    float*    cent   = (float*)   (ws + 75759616);  // 131072 B centroid mailboxes

    prep_kernel<<<32, 256, 0, stream>>>(w0, w1, w2, w0b, w1b, w2b, accum0, cent);
    // mega: blocks 0..7 = fps producers; blocks 8..4103 = qball+layer0 workers
    // overlapped under the fps serial shadow.
    mega_kernel<<<NB + 4096, 256, 0, stream>>>(xyz, pts, w0b, b0, z0, accum0, cent, out);
    layer1_mfma<<<512, 256, 0, stream>>>(z0, accum0, g0, be0, w1b, b1, z1, accum1);
    layer2_mfma<<<512, 256, 0, stream>>>(z1, accum1, g1, be1, w2b, b2, pool, accum2);
    final_kernel<<<512, 256, 0, stream>>>(pool, accum2, g2, be2, out);
}

// Round 7
// 752.995 us; speedup vs baseline: 2.2927x; 1.0048x over previous
//
#include <hip/hip_runtime.h>
#include <stdint.h>

#define NB 8
#define NPTS 4096
#define NS 1024
#define NK 32
#define NROWS (NB*NS*NK)   // 262144
#define R2 0.04f
#define NCOPY 8            // atomic spreading copies for stats accum

typedef __attribute__((ext_vector_type(8))) short bf16x8;   // 8 bf16 in 4 VGPRs
typedef __attribute__((ext_vector_type(4))) float f32x4;    // MFMA 16x16 accumulator
typedef __attribute__((ext_vector_type(2))) float f32x2;    // packed fp32 (v_pk_*)

__device__ __forceinline__ float bf2f(uint16_t u){
    uint32_t v = ((uint32_t)u) << 16;
    return __uint_as_float(v);
}
__device__ __forceinline__ uint16_t f2bf(float f){
    uint32_t u = __float_as_uint(f);
    uint32_t r = (u + 0x7FFFu + ((u >> 16) & 1u)) >> 16;
    return (uint16_t)r;
}
__device__ __forceinline__ bf16x8 load_bf8(const uint16_t* p){
    return *reinterpret_cast<const bf16x8*>(p);
}

// SESSION LESSONS (measured):
//  - R2: per-block device-scope fences / acq_rel atomics are POISON on gfx950
//    (L2 wb/inv storm, +900us over 8k blocks). Plain atomicAdd is fine.
//  - R3: BAR_LGKM + wave-split publish REGRESSED mega 635->668. Keep __syncthreads.
//  - R4: batched publish == per-iter publish == 634us. The +52us vs standalone
//    fps (583) is LOAD-DEPENDENT CLOCK DROOP, not store-drain. Mega is at its
//    structural floor (632-634 over 15 dispatches); don't re-attack.
//  - R5: downstream is LATENCY-bound, not BW-bound (120MB ideal = 19us, was
//    ~115us). R6: prefetch pipeline + full-residency grids + coalesced final.
//  - R6 bench: "container failed twice" = infra flake (no pytest/profile ran);
//    kernel re-audited clean, resubmitted verbatim.

// ---------------------------------------------------------------- producer/consumer plumbing
__device__ __forceinline__ void publish_cent4(float* cent, int cell0,
                                              f32x4 c0, f32x4 c1, f32x4 c2, f32x4 c3){
    unsigned long long a = (unsigned long long)(uintptr_t)(cent + (size_t)cell0*4);
    asm volatile("global_store_dwordx4 %0, %1, off sc0 sc1\n\t"
                 "global_store_dwordx4 %0, %2, off offset:16 sc0 sc1\n\t"
                 "global_store_dwordx4 %0, %3, off offset:32 sc0 sc1\n\t"
                 "global_store_dwordx4 %0, %4, off offset:48 sc0 sc1"
                 :: "v"(a), "v"(c0), "v"(c1), "v"(c2), "v"(c3)
                 : "memory");
}
__device__ __forceinline__ f32x4 wait_cent(const float* cent, int cell){
    const uint32_t* wp = (const uint32_t*)(cent + (size_t)cell*4) + 3;
    while (__hip_atomic_load(wp, __ATOMIC_RELAXED, __HIP_MEMORY_SCOPE_AGENT)
           != 0x3F800000u)
        __builtin_amdgcn_s_sleep(64);
    f32x4 r;
    unsigned long long a = (unsigned long long)(uintptr_t)(cent + (size_t)cell*4);
    asm volatile("global_load_dwordx4 %0, %1, off sc0 sc1\n\ts_waitcnt vmcnt(0)"
                 : "=v"(r) : "v"(a) : "memory");
    return r;
}

#define DPPMAX64(key, ctrl, rmask)                                             \
    {                                                                          \
        uint32_t _lo = (uint32_t)(key), _hi = (uint32_t)((key) >> 32);         \
        uint32_t _olo = (uint32_t)__builtin_amdgcn_update_dpp(                 \
            0, (int)_lo, (ctrl), (rmask), 0xf, true);                          \
        uint32_t _ohi = (uint32_t)__builtin_amdgcn_update_dpp(                 \
            0, (int)_hi, (ctrl), (rmask), 0xf, true);                          \
        unsigned long long _o = (((unsigned long long)_ohi) << 32) | _olo;     \
        key = (_o > (key)) ? _o : (key);                                       \
    }

// ---------------------------------------------------------------- mega-kernel shared union
struct FpsSh {
    float LX[NPTS], LY[NPTS], LZ[NPTS];
    f32x4 SC[NS];
    alignas(16) unsigned long long cand[2][4];
};
struct WrkSh {
    float S_s[16][64], S_q[16][64];
    int   idxL[2][NK];
    f32x4 Lc[2];
};
union MegaSh { FpsSh f; WrkSh w; char force_one_block_per_cu[86016]; };

// ---------------------------------------------------------------- mega (UNCHANGED from r5 — at structural floor)
#define FT 16
__global__ __launch_bounds__(256) void mega_kernel(const float* __restrict__ xyz,
                                                   const float* __restrict__ pts,
                                                   const uint16_t* __restrict__ w0b,
                                                   const float* __restrict__ b0,
                                                   uint16_t* __restrict__ z0,
                                                   double* __restrict__ accumOut,
                                                   float* __restrict__ cent,
                                                   float* __restrict__ out_newxyz){
    __shared__ MegaSh sh;
    const int t = threadIdx.x;

    if (blockIdx.x < NB){
        const int b = blockIdx.x;
        const float* base = xyz + (size_t)b * (NPTS*3);
        f32x2 px2[FT/2], py2[FT/2], pz2[FT/2], pd2[FT/2];
#pragma unroll
        for (int j = 0; j < FT/2; ++j){
            int i = t*FT + 2*j;
            float x0 = base[i*3+0], y0 = base[i*3+1], z0c = base[i*3+2];
            float x1 = base[i*3+3], y1 = base[i*3+4], z1c = base[i*3+5];
            px2[j] = (f32x2){x0, x1};
            py2[j] = (f32x2){y0, y1};
            pz2[j] = (f32x2){z0c, z1c};
            pd2[j] = (f32x2){1e10f, 1e10f};
            sh.f.LX[i]=x0; sh.f.LY[i]=y0; sh.f.LZ[i]=z0c;
            sh.f.LX[i+1]=x1; sh.f.LY[i+1]=y1; sh.f.LZ[i+1]=z1c;
        }
        __syncthreads();
        int cur = 0;
        const int wave = t >> 6, lane = t & 63;
        f32x4 pb0, pb1, pb2, pb3;
        for (int s4 = 0; s4 < NS; s4 += 4){
            if (s4 && t == 0)
                publish_cent4(cent, b*NS + (s4 - 4), pb0, pb1, pb2, pb3);
#pragma unroll
            for (int u = 0; u < 4; ++u){
                const int s = s4 + u;
                float cx = sh.f.LX[cur], cy = sh.f.LY[cur], cz = sh.f.LZ[cur];
                if (t == 0){
                    sh.f.SC[s] = (f32x4){cx, cy, cz, 0.f};
                    f32x4 c = (f32x4){cx, cy, cz, 1.0f};
                    if (u == 0) pb0 = c; else if (u == 1) pb1 = c;
                    else if (u == 2) pb2 = c; else pb3 = c;
                }
                f32x2 ncx = (f32x2){-cx, -cx};
                f32x2 ncy = (f32x2){-cy, -cy};
                f32x2 ncz = (f32x2){-cz, -cz};
                float bestd = -1.0f; int besti = 0;
#pragma unroll
                for (int j = 0; j < FT/2; ++j){
                    f32x2 d2;
                    {
#pragma clang fp contract(off)
                        f32x2 dx = px2[j] + ncx;       // pk_add; == px - cx bit-exact
                        f32x2 dy = py2[j] + ncy;
                        f32x2 dz = pz2[j] + ncz;
                        f32x2 xx = dx*dx, yy = dy*dy, zz = dz*dz;
                        d2 = (xx + yy) + zz;
                    }
                    f32x2 nd;
                    nd.x = fminf(pd2[j].x, d2.x);
                    nd.y = fminf(pd2[j].y, d2.y);
                    pd2[j] = nd;
                    if (nd.x > bestd){ bestd = nd.x; besti = t*FT + 2*j; }
                    if (nd.y > bestd){ bestd = nd.y; besti = t*FT + 2*j + 1; }
                }
                unsigned long long key =
                    (((unsigned long long)__float_as_uint(bestd)) << 32) |
                    (unsigned long long)(~(unsigned)besti);
                DPPMAX64(key, 0x111, 0xf);   // row_shr:1
                DPPMAX64(key, 0x112, 0xf);   // row_shr:2
                DPPMAX64(key, 0x114, 0xf);   // row_shr:4
                DPPMAX64(key, 0x118, 0xf);   // row_shr:8
                DPPMAX64(key, 0x142, 0xa);   // row_bcast:15 -> rows 1,3
                DPPMAX64(key, 0x143, 0xc);   // row_bcast:31 -> rows 2,3
                int p = s & 1;
                if (lane == 63) sh.f.cand[p][wave] = key;
                __syncthreads();
                ulonglong2 c01 = *reinterpret_cast<const ulonglong2*>(&sh.f.cand[p][0]);
                ulonglong2 c23 = *reinterpret_cast<const ulonglong2*>(&sh.f.cand[p][2]);
                unsigned long long m01 = (c01.x > c01.y) ? c01.x : c01.y;
                unsigned long long m23 = (c23.x > c23.y) ? c23.x : c23.y;
                unsigned long long km  = (m01 > m23) ? m01 : m23;
                cur = (int)(~(uint32_t)km);
            }
        }
        if (t == 0)
            publish_cent4(cent, b*NS + (NS - 4), pb0, pb1, pb2, pb3);
        __syncthreads();
        for (int i = t; i < NS; i += 256){
            f32x4 c = sh.f.SC[i];
            float* o = out_newxyz + ((size_t)b*NS + i)*3;
            o[0] = c[0]; o[1] = c[1]; o[2] = c[2];
        }
    } else {
        const int w = (int)blockIdx.x - NB;
        const int stile = w >> 3;
        const int b = w & 7;
        const int wave = t >> 6, lane = t & 63;
        const int q = lane >> 4, l16 = lane & 15;

        bf16x8 Bf[4][3];
#pragma unroll
        for (int nt = 0; nt < 4; ++nt)
#pragma unroll
            for (int s = 0; s < 3; ++s)
                Bf[nt][s] = load_bf8(w0b + (nt*16 + l16)*96 + s*32 + q*8);

        if (t == 0){
            sh.w.Lc[0] = wait_cent(cent, b*NS + stile*2 + 0);
            sh.w.Lc[1] = wait_cent(cent, b*NS + stile*2 + 1);
        }
        __syncthreads();

        if (wave < 2){
            f32x4 qc = sh.w.Lc[wave];
            float qx = qc[0], qy = qc[1], qz = qc[2];
            float qn = qx*qx;
            qn = fmaf(qy, qy, qn);
            qn = fmaf(qz, qz, qn);
            const float* base = xyz + (size_t)b * (NPTS*3);
            int cnt = 0, first = 0;
            for (int c0 = 0; c0 < NPTS; c0 += 64){
                int i = c0 + lane;
                float x = base[i*3+0], y = base[i*3+1], z = base[i*3+2];
                float xn = x*x;
                xn = fmaf(y, y, xn);
                xn = fmaf(z, z, xn);
                float dot = qx*x;
                dot = fmaf(qy, y, dot);
                dot = fmaf(qz, z, dot);
                float d;
                {
#pragma clang fp contract(off)
                    d = -2.0f * dot;
                    d = d + qn;
                    d = d + xn;
                }
                bool in = !(d > R2);
                unsigned long long m = __ballot(in);
                if (in){
                    int rank = __popcll(m & ((1ull << lane) - 1ull));
                    int pos = cnt + rank;
                    if (pos < NK) sh.w.idxL[wave][pos] = i;
                }
                if (cnt == 0 && m) first = c0 + (__ffsll((unsigned long long)m) - 1);
                cnt += __popcll(m);
                if (cnt >= NK) break;
            }
            if (cnt < NK){
                for (int p = cnt + lane; p < NK; p += 64) sh.w.idxL[wave][p] = first;
            }
        }
        __syncthreads();

        const int rowbase = (b*NS + stile*2)*NK;
        const int r0 = rowbase + wave*16;
        const int cell = wave >> 1;
        const int sample = (wave & 1)*16 + l16;
        const int id = sh.w.idxL[cell][sample];
        const float* prow = pts + (((size_t)b << 12) + id)*64;
        const float* xr   = xyz + (((size_t)b << 12) + id)*3;
        f32x4 qc = sh.w.Lc[cell];
        float d0 = xr[0]-qc[0], d1 = xr[1]-qc[1], d2 = xr[2]-qc[2];

        f32x4 acc[4];
#pragma unroll
        for (int nt = 0; nt < 4; ++nt) acc[nt] = (f32x4){0.f,0.f,0.f,0.f};

#pragma unroll
        for (int s = 0; s < 3; ++s){
            const int k0 = s*32 + q*8;
            bf16x8 a;
#pragma unroll
            for (int j = 0; j < 8; ++j){
                int k = k0 + j;
                float v = (k < 3) ? ((k == 0) ? d0 : ((k == 1) ? d1 : d2))
                                  : ((k < 67) ? prow[k-3] : 0.f);
                a[j] = (short)f2bf(v);
            }
#pragma unroll
            for (int nt = 0; nt < 4; ++nt)
                acc[nt] = __builtin_amdgcn_mfma_f32_16x16x32_bf16(a, Bf[nt][s], acc[nt], 0, 0, 0);
        }
#pragma unroll
        for (int nt = 0; nt < 4; ++nt){
            int c = nt*16 + l16;
            float bb = b0[c];
            float sps = 0.f, spq = 0.f;
#pragma unroll
            for (int reg = 0; reg < 4; ++reg){
                int rr = r0 + q*4 + reg;
                float h = acc[nt][reg] + bb;
                sps += h;
                spq = fmaf(h, h, spq);
                z0[(size_t)rr*64 + c] = f2bf(h);
            }
            sh.w.S_s[wave*4 + q][c] = sps;
            sh.w.S_q[wave*4 + q][c] = spq;
        }
        __syncthreads();
        if (t < 64){
            double ss = 0.0, sq = 0.0;
#pragma unroll
            for (int i = 0; i < 16; ++i){ ss += (double)sh.w.S_s[i][t]; sq += (double)sh.w.S_q[i][t]; }
            int cp = blockIdx.x & (NCOPY-1);
            atomicAdd(&accumOut[cp*256 + t], ss);
            atomicAdd(&accumOut[cp*256 + 128 + t], sq);
        }
    }
}

// ---------------------------------------------------------------- weight prep (fp32 -> bf16) + accum zeroing + cent flag clear
__global__ void prep_kernel(const float* __restrict__ w0, const float* __restrict__ w1,
                            const float* __restrict__ w2, uint16_t* __restrict__ w0b,
                            uint16_t* __restrict__ w1b, uint16_t* __restrict__ w2b,
                            double* __restrict__ accumAll, float* __restrict__ cent){
    int t = blockIdx.x*256 + threadIdx.x;
    int stride = gridDim.x*256;
    for (int i = t; i < 3*NCOPY*256; i += stride) accumAll[i] = 0.0;
    for (int i = t; i < NB*NS; i += stride)
        ((f32x4*)cent)[i] = (f32x4){0.f, 0.f, 0.f, 0.f};
    for (int i = t; i < 64*96; i += stride){
        int n = i/96, c = i%96;
        w0b[i] = (c < 67) ? f2bf(w0[n*67 + c]) : (uint16_t)0;
    }
    for (int i = t; i < 64*64; i += stride)  w1b[i] = f2bf(w1[i]);
    for (int i = t; i < 128*64; i += stride) w2b[i] = f2bf(w2[i]);
}

// ---------------------------------------------------------------- layer 1: BN+relu+GEMM K=64 + fused stats
// r6: grid 1024 x TPB=4 (exactly 4 blocks/CU full residency) + NEXT-TILE
// PREFETCH: tile+1's z loads issue before tile's compute -> HBM latency hides
// under convert+MFMA+stores. Register-carried stats, one exchange at end.
__global__ __launch_bounds__(256) void layer1_mfma(const uint16_t* __restrict__ zin,
                                                   const double* __restrict__ accumIn,
                                                   const float* __restrict__ g,
                                                   const float* __restrict__ be,
                                                   const uint16_t* __restrict__ wb,
                                                   const float* __restrict__ bias,
                                                   uint16_t* __restrict__ zout,
                                                   double* __restrict__ accumOut){
    constexpr int NT = 4;
    constexpr int TPB = 4;
    __shared__ float sc_l[64], sh_l[64];
    __shared__ float S_s[16][64], S_q[16][64];
    const int t = threadIdx.x;
    if (t < 64){
        double s = 0.0, qq = 0.0;
#pragma unroll
        for (int cp = 0; cp < NCOPY; ++cp){
            s  += accumIn[cp*256 + t];
            qq += accumIn[cp*256 + 128 + t];
        }
        double mean = s / (double)NROWS;
        double var  = qq / (double)NROWS - mean*mean;
        double rs = 1.0 / sqrt(var + 1e-5);
        double scv = (double)g[t] * rs;
        sc_l[t] = (float)scv;
        sh_l[t] = (float)((double)be[t] - mean*scv);
    }
    __syncthreads();

    const int wave = t >> 6, lane = t & 63;
    const int q = lane >> 4, l16 = lane & 15;

    bf16x8 Bf[NT][2];
#pragma unroll
    for (int nt = 0; nt < NT; ++nt)
#pragma unroll
        for (int s = 0; s < 2; ++s)
            Bf[nt][s] = load_bf8(wb + (nt*16 + l16)*64 + s*32 + q*8);

    float sc[2][8], sh[2][8];
#pragma unroll
    for (int s = 0; s < 2; ++s)
#pragma unroll
        for (int j = 0; j < 8; ++j){
            sc[s][j] = sc_l[s*32 + q*8 + j];
            sh[s][j] = sh_l[s*32 + q*8 + j];
        }

    float statS[NT], statQ[NT];
#pragma unroll
    for (int nt = 0; nt < NT; ++nt){ statS[nt] = 0.f; statQ[nt] = 0.f; }
    float bb[NT];
#pragma unroll
    for (int nt = 0; nt < NT; ++nt) bb[nt] = bias[nt*16 + l16];

    // software pipeline: prime tile 0, prefetch tile+1 before computing tile
    const uint16_t* zb = zin + ((size_t)(blockIdx.x*TPB)*64 + wave*16 + l16)*64;
    uint4 cu0 = *reinterpret_cast<const uint4*>(zb + q*8);
    uint4 cu1 = *reinterpret_cast<const uint4*>(zb + 32 + q*8);

#pragma unroll
    for (int tile = 0; tile < TPB; ++tile){
        uint4 nu0 = cu0, nu1 = cu1;
        if (tile + 1 < TPB){
            const uint16_t* zn = zb + (size_t)(tile+1)*4096;   // 64 rows * 64 ch
            nu0 = *reinterpret_cast<const uint4*>(zn + q*8);
            nu1 = *reinterpret_cast<const uint4*>(zn + 32 + q*8);
        }
        const int r0 = (blockIdx.x*TPB + tile)*64 + wave*16;

        f32x4 acc[NT];
#pragma unroll
        for (int nt = 0; nt < NT; ++nt) acc[nt] = (f32x4){0.f,0.f,0.f,0.f};

        uint4 uu[2] = {cu0, cu1};
#pragma unroll
        for (int s = 0; s < 2; ++s){
            uint4 u = uu[s];
            float h[8];
            h[0] = bf2f((uint16_t)(u.x & 0xFFFF)); h[1] = bf2f((uint16_t)(u.x >> 16));
            h[2] = bf2f((uint16_t)(u.y & 0xFFFF)); h[3] = bf2f((uint16_t)(u.y >> 16));
            h[4] = bf2f((uint16_t)(u.z & 0xFFFF)); h[5] = bf2f((uint16_t)(u.z >> 16));
            h[6] = bf2f((uint16_t)(u.w & 0xFFFF)); h[7] = bf2f((uint16_t)(u.w >> 16));
            bf16x8 a;
#pragma unroll
            for (int j = 0; j < 8; ++j){
                float v = fmaxf(fmaf(h[j], sc[s][j], sh[s][j]), 0.f);
                a[j] = (short)f2bf(v);
            }
#pragma unroll
            for (int nt = 0; nt < NT; ++nt)
                acc[nt] = __builtin_amdgcn_mfma_f32_16x16x32_bf16(a, Bf[nt][s], acc[nt], 0, 0, 0);
        }
#pragma unroll
        for (int nt = 0; nt < NT; ++nt){
            int c = nt*16 + l16;
#pragma unroll
            for (int reg = 0; reg < 4; ++reg){
                int rr = r0 + q*4 + reg;
                float h = acc[nt][reg] + bb[nt];
                statS[nt] += h;
                statQ[nt] = fmaf(h, h, statQ[nt]);
                zout[(size_t)rr*64 + c] = f2bf(h);
            }
        }
        cu0 = nu0; cu1 = nu1;
    }
    // one LDS stats exchange for the whole block
#pragma unroll
    for (int nt = 0; nt < NT; ++nt){
        int c = nt*16 + l16;
        S_s[wave*4 + q][c] = statS[nt];
        S_q[wave*4 + q][c] = statQ[nt];
    }
    __syncthreads();
    if (t < 64){
        double ss = 0.0, sq = 0.0;
#pragma unroll
        for (int i = 0; i < 16; ++i){ ss += (double)S_s[i][t]; sq += (double)S_q[i][t]; }
        int cp = blockIdx.x & (NCOPY-1);
        atomicAdd(&accumOut[cp*256 + t], ss);
        atomicAdd(&accumOut[cp*256 + 128 + t], sq);
    }
}

// ---------------------------------------------------------------- layer 2: BN+relu+GEMM K=64 -> 128 + fused stats + pooling
// r6: grid 1024 x TPB=4 + next-tile prefetch; stats exchange reuses the
// pooling LDS (P_mx/P_mn) after the last pooling barrier (-16KB LDS).
__global__ __launch_bounds__(256) void layer2_mfma(const uint16_t* __restrict__ zin,
                                                   const double* __restrict__ accumIn,
                                                   const float* __restrict__ g,
                                                   const float* __restrict__ be,
                                                   const uint16_t* __restrict__ wb,
                                                   const float* __restrict__ bias,
                                                   float2* __restrict__ pool,
                                                   double* __restrict__ accumOut){
    constexpr int NT = 8;
    constexpr int TPB = 4;
    __shared__ float sc_l[64], sh_l[64];
    __shared__ float P_mx[16][128], P_mn[16][128];   // pooling; reused for stats at end
    const int t = threadIdx.x;
    if (t < 64){
        double s = 0.0, qq = 0.0;
#pragma unroll
        for (int cp = 0; cp < NCOPY; ++cp){
            s  += accumIn[cp*256 + t];
            qq += accumIn[cp*256 + 128 + t];
        }
        double mean = s / (double)NROWS;
        double var  = qq / (double)NROWS - mean*mean;
        double rs = 1.0 / sqrt(var + 1e-5);
        double scv = (double)g[t] * rs;
        sc_l[t] = (float)scv;
        sh_l[t] = (float)((double)be[t] - mean*scv);
    }
    __syncthreads();

    const int wave = t >> 6, lane = t & 63;
    const int q = lane >> 4, l16 = lane & 15;

    bf16x8 Bf[NT][2];
#pragma unroll
    for (int nt = 0; nt < NT; ++nt)
#pragma unroll
        for (int s = 0; s < 2; ++s)
            Bf[nt][s] = load_bf8(wb + (nt*16 + l16)*64 + s*32 + q*8);

    float sc[2][8], sh[2][8];
#pragma unroll
    for (int s = 0; s < 2; ++s)
#pragma unroll
        for (int j = 0; j < 8; ++j){
            sc[s][j] = sc_l[s*32 + q*8 + j];
            sh[s][j] = sh_l[s*32 + q*8 + j];
        }

    float statS[NT], statQ[NT];
#pragma unroll
    for (int nt = 0; nt < NT; ++nt){ statS[nt] = 0.f; statQ[nt] = 0.f; }
    float bb[NT];
#pragma unroll
    for (int nt = 0; nt < NT; ++nt) bb[nt] = bias[nt*16 + l16];

    const uint16_t* zb = zin + ((size_t)(blockIdx.x*TPB)*64 + wave*16 + l16)*64;
    uint4 cu0 = *reinterpret_cast<const uint4*>(zb + q*8);
    uint4 cu1 = *reinterpret_cast<const uint4*>(zb + 32 + q*8);

#pragma unroll
    for (int tile = 0; tile < TPB; ++tile){
        uint4 nu0 = cu0, nu1 = cu1;
        if (tile + 1 < TPB){
            const uint16_t* zn = zb + (size_t)(tile+1)*4096;
            nu0 = *reinterpret_cast<const uint4*>(zn + q*8);
            nu1 = *reinterpret_cast<const uint4*>(zn + 32 + q*8);
        }

        f32x4 acc[NT];
#pragma unroll
        for (int nt = 0; nt < NT; ++nt) acc[nt] = (f32x4){0.f,0.f,0.f,0.f};

        uint4 uu[2] = {cu0, cu1};
#pragma unroll
        for (int s = 0; s < 2; ++s){
            uint4 u = uu[s];
            float h[8];
            h[0] = bf2f((uint16_t)(u.x & 0xFFFF)); h[1] = bf2f((uint16_t)(u.x >> 16));
            h[2] = bf2f((uint16_t)(u.y & 0xFFFF)); h[3] = bf2f((uint16_t)(u.y >> 16));
            h[4] = bf2f((uint16_t)(u.z & 0xFFFF)); h[5] = bf2f((uint16_t)(u.z >> 16));
            h[6] = bf2f((uint16_t)(u.w & 0xFFFF)); h[7] = bf2f((uint16_t)(u.w >> 16));
            bf16x8 a;
#pragma unroll
            for (int j = 0; j < 8; ++j){
                float v = fmaxf(fmaf(h[j], sc[s][j], sh[s][j]), 0.f);
                a[j] = (short)f2bf(v);
            }
#pragma unroll
            for (int nt = 0; nt < NT; ++nt)
                acc[nt] = __builtin_amdgcn_mfma_f32_16x16x32_bf16(a, Bf[nt][s], acc[nt], 0, 0, 0);
        }
#pragma unroll
        for (int nt = 0; nt < NT; ++nt){
            int c = nt*16 + l16;
            float mx = -1e30f, mn = 1e30f;
#pragma unroll
            for (int reg = 0; reg < 4; ++reg){
                float h = acc[nt][reg] + bb[nt];
                statS[nt] += h;
                statQ[nt] = fmaf(h, h, statQ[nt]);
                mx = fmaxf(mx, h);
                mn = fminf(mn, h);
            }
            P_mx[wave*4 + q][c] = mx;
            P_mn[wave*4 + q][c] = mn;
        }
        __syncthreads();
        {
            int gidx = t >> 7;          // 0..1
            int c = t & 127;
            float mx = -1e30f, mn = 1e30f;
#pragma unroll
            for (int i = 0; i < 8; ++i){
                mx = fmaxf(mx, P_mx[gidx*8 + i][c]);
                mn = fminf(mn, P_mn[gidx*8 + i][c]);
            }
            pool[(size_t)((blockIdx.x*TPB + tile)*2 + gidx)*128 + c] = make_float2(mx, mn);
        }
        __syncthreads();
        cu0 = nu0; cu1 = nu1;
    }
    // stats exchange, reusing pooling LDS (safe: last pooling read barriered above)
#pragma unroll
    for (int nt = 0; nt < NT; ++nt){
        int c = nt*16 + l16;
        P_mx[wave*4 + q][c] = statS[nt];
        P_mn[wave*4 + q][c] = statQ[nt];
    }
    __syncthreads();
    if (t < 128){
        double ss = 0.0, sq = 0.0;
#pragma unroll
        for (int i = 0; i < 16; ++i){ ss += (double)P_mx[i][t]; sq += (double)P_mn[i][t]; }
        int cp = blockIdx.x & (NCOPY-1);
        atomicAdd(&accumOut[cp*256 + t], ss);
        atomicAdd(&accumOut[cp*256 + 128 + t], sq);
    }
}

// ---------------------------------------------------------------- final: BN-param + select + relu + COALESCED transpose via LDS
// r6: one (b, 32-s slice) per block (grid 256). Reads pool coalesced (lanes
// span o: 1KB/row), applies BN+select on load into padded LDS [128][33]
// (2-way bank max), then writes out with 128B-contiguous s-runs. Old version
// wrote 4B/lane at 4KB stride (scattered, ~8x write amplification).
__global__ __launch_bounds__(256) void final_kernel(const float2* __restrict__ pool,
                                                    const double* __restrict__ accumIn,
                                                    const float* __restrict__ g,
                                                    const float* __restrict__ be,
                                                    float* __restrict__ out){
    __shared__ float sc_l[128], sh_l[128];
    __shared__ float Y[128][33];
    const int t = threadIdx.x;
    if (t < 128){
        double s = 0.0, qq = 0.0;
#pragma unroll
        for (int cp = 0; cp < NCOPY; ++cp){
            s  += accumIn[cp*256 + t];
            qq += accumIn[cp*256 + 128 + t];
        }
        double mean = s / (double)NROWS;
        double var  = qq / (double)NROWS - mean*mean;
        double rs = 1.0 / sqrt(var + 1e-5);
        double scv = (double)g[t] * rs;
        sc_l[t] = (float)scv;
        sh_l[t] = (float)((double)be[t] - mean*scv);
    }
    __syncthreads();

    const int b  = blockIdx.x >> 5;          // 0..7
    const int s0 = (blockIdx.x & 31) * 32;   // s slice base
    const int o  = t & 127;
    const int shalf = t >> 7;                // 0..1
    const float scv = sc_l[o], shv = sh_l[o];
#pragma unroll
    for (int it = 0; it < 16; ++it){
        int sl = it*2 + shalf;
        float2 p = pool[((size_t)(b*NS + s0 + sl))*128 + o];
        float zsel = (scv >= 0.f) ? p.x : p.y;
        Y[o][sl] = fmaxf(fmaf(zsel, scv, shv), 0.f);
    }
    __syncthreads();
#pragma unroll
    for (int pass = 0; pass < 16; ++pass){
        int oo = pass*8 + (t >> 5);
        int sl = t & 31;
        out[24576 + ((size_t)b << 17) + ((size_t)oo << 10) + s0 + sl] = Y[oo][sl];
    }
}

// ---------------------------------------------------------------- launch
extern "C" void kernel_launch(void* const* d_in, const int* in_sizes, int n_in,
                              void* d_out, int out_size, void* d_ws, size_t ws_size,
                              hipStream_t stream) {
    const float* xyz = (const float*)d_in[0];
    const float* pts = (const float*)d_in[1];
    const float* w0  = (const float*)d_in[2];
    const float* b0  = (const float*)d_in[3];
    const float* g0  = (const float*)d_in[4];
    const float* be0 = (const float*)d_in[5];
    const float* w1  = (const float*)d_in[6];
    const float* b1  = (const float*)d_in[7];
    const float* g1  = (const float*)d_in[8];
    const float* be1 = (const float*)d_in[9];
    const float* w2  = (const float*)d_in[10];
    const float* b2  = (const float*)d_in[11];
    const float* g2  = (const float*)d_in[12];
    const float* be2 = (const float*)d_in[13];
    float* out = (float*)d_out;

    char* ws = (char*)d_ws;
    double*   accum0 = (double*)(ws + 0);
    double*   accum1 = (double*)(ws + 65536);
    double*   accum2 = (double*)(ws + 131072);
    uint16_t* w0b    = (uint16_t*)(ws + 196608);    // 12288 B
    uint16_t* w1b    = (uint16_t*)(ws + 208896);    // 8192 B
    uint16_t* w2b    = (uint16_t*)(ws + 217088);    // 16384 B
    uint16_t* z0     = (uint16_t*)(ws + 262144);    // 33554432 B
    uint16_t* z1     = (uint16_t*)(ws + 33816576);  // 33554432 B
    float2*   pool   = (float2*)  (ws + 67371008);  // 8388608 B
    float*    cent   = (float*)   (ws + 75759616);  // 131072 B centroid mailboxes

    prep_kernel<<<32, 256, 0, stream>>>(w0, w1, w2, w0b, w1b, w2b, accum0, cent);
    mega_kernel<<<NB + 4096, 256, 0, stream>>>(xyz, pts, w0b, b0, z0, accum0, cent, out);
    layer1_mfma<<<1024, 256, 0, stream>>>(z0, accum0, g0, be0, w1b, b1, z1, accum1);
    layer2_mfma<<<1024, 256, 0, stream>>>(z1, accum1, g1, be1, w2b, b2, pool, accum2);
    final_kernel<<<256, 256, 0, stream>>>(pool, accum2, g2, be2, out);
}

// Round 8
// 752.644 us; speedup vs baseline: 2.2938x; 1.0005x over previous
//
#include <hip/hip_runtime.h>
#include <stdint.h>

#define NB 8
#define NPTS 4096
#define NS 1024
#define NK 32
#define NROWS (NB*NS*NK)   // 262144
#define R2 0.04f
#define NCOPY 8            // atomic spreading copies for stats accum

typedef __attribute__((ext_vector_type(8))) short bf16x8;   // 8 bf16 in 4 VGPRs
typedef __attribute__((ext_vector_type(4))) float f32x4;    // MFMA 16x16 accumulator
typedef __attribute__((ext_vector_type(2))) float f32x2;    // packed fp32 (v_pk_*)

__device__ __forceinline__ float bf2f(uint16_t u){
    uint32_t v = ((uint32_t)u) << 16;
    return __uint_as_float(v);
}
__device__ __forceinline__ uint16_t f2bf(float f){
    uint32_t u = __float_as_uint(f);
    uint32_t r = (u + 0x7FFFu + ((u >> 16) & 1u)) >> 16;
    return (uint16_t)r;
}
__device__ __forceinline__ bf16x8 load_bf8(const uint16_t* p){
    return *reinterpret_cast<const bf16x8*>(p);
}

// SESSION LESSONS (measured):
//  - R2: per-block device-scope fences / acq_rel atomics are POISON on gfx950
//    (L2 wb/inv storm, +900us over 8k blocks). Plain atomicAdd is fine.
//  - R3: BAR_LGKM + wave-split publish REGRESSED mega 635->668. Keep __syncthreads.
//  - R4: batched publish == per-iter publish == 634us. The +52us vs standalone
//    fps (583) is LOAD-DEPENDENT CLOCK DROOP, not store-drain. Mega is at its
//    structural floor (632-638 over 20+ dispatches); don't re-attack.
//  - R7: prefetch/residency barely moved downstream (-7us) -> not load-latency.
//    Remaining 1st-order defect: layer1's 16x 2B scattered z-stores/thread
//    (~8x transaction amplification on 33MB). R8: LDS-staged coalesced stores.

// ---------------------------------------------------------------- producer/consumer plumbing
__device__ __forceinline__ void publish_cent4(float* cent, int cell0,
                                              f32x4 c0, f32x4 c1, f32x4 c2, f32x4 c3){
    unsigned long long a = (unsigned long long)(uintptr_t)(cent + (size_t)cell0*4);
    asm volatile("global_store_dwordx4 %0, %1, off sc0 sc1\n\t"
                 "global_store_dwordx4 %0, %2, off offset:16 sc0 sc1\n\t"
                 "global_store_dwordx4 %0, %3, off offset:32 sc0 sc1\n\t"
                 "global_store_dwordx4 %0, %4, off offset:48 sc0 sc1"
                 :: "v"(a), "v"(c0), "v"(c1), "v"(c2), "v"(c3)
                 : "memory");
}
__device__ __forceinline__ f32x4 wait_cent(const float* cent, int cell){
    const uint32_t* wp = (const uint32_t*)(cent + (size_t)cell*4) + 3;
    while (__hip_atomic_load(wp, __ATOMIC_RELAXED, __HIP_MEMORY_SCOPE_AGENT)
           != 0x3F800000u)
        __builtin_amdgcn_s_sleep(64);
    f32x4 r;
    unsigned long long a = (unsigned long long)(uintptr_t)(cent + (size_t)cell*4);
    asm volatile("global_load_dwordx4 %0, %1, off sc0 sc1\n\ts_waitcnt vmcnt(0)"
                 : "=v"(r) : "v"(a) : "memory");
    return r;
}

#define DPPMAX64(key, ctrl, rmask)                                             \
    {                                                                          \
        uint32_t _lo = (uint32_t)(key), _hi = (uint32_t)((key) >> 32);         \
        uint32_t _olo = (uint32_t)__builtin_amdgcn_update_dpp(                 \
            0, (int)_lo, (ctrl), (rmask), 0xf, true);                          \
        uint32_t _ohi = (uint32_t)__builtin_amdgcn_update_dpp(                 \
            0, (int)_hi, (ctrl), (rmask), 0xf, true);                          \
        unsigned long long _o = (((unsigned long long)_ohi) << 32) | _olo;     \
        key = (_o > (key)) ? _o : (key);                                       \
    }

// ---------------------------------------------------------------- mega-kernel shared union
struct FpsSh {
    float LX[NPTS], LY[NPTS], LZ[NPTS];
    f32x4 SC[NS];
    alignas(16) unsigned long long cand[2][4];
};
struct WrkSh {
    float S_s[16][64], S_q[16][64];
    int   idxL[2][NK];
    f32x4 Lc[2];
};
union MegaSh { FpsSh f; WrkSh w; char force_one_block_per_cu[86016]; };

// ---------------------------------------------------------------- mega (UNCHANGED — at structural floor)
#define FT 16
__global__ __launch_bounds__(256) void mega_kernel(const float* __restrict__ xyz,
                                                   const float* __restrict__ pts,
                                                   const uint16_t* __restrict__ w0b,
                                                   const float* __restrict__ b0,
                                                   uint16_t* __restrict__ z0,
                                                   double* __restrict__ accumOut,
                                                   float* __restrict__ cent,
                                                   float* __restrict__ out_newxyz){
    __shared__ MegaSh sh;
    const int t = threadIdx.x;

    if (blockIdx.x < NB){
        const int b = blockIdx.x;
        const float* base = xyz + (size_t)b * (NPTS*3);
        f32x2 px2[FT/2], py2[FT/2], pz2[FT/2], pd2[FT/2];
#pragma unroll
        for (int j = 0; j < FT/2; ++j){
            int i = t*FT + 2*j;
            float x0 = base[i*3+0], y0 = base[i*3+1], z0c = base[i*3+2];
            float x1 = base[i*3+3], y1 = base[i*3+4], z1c = base[i*3+5];
            px2[j] = (f32x2){x0, x1};
            py2[j] = (f32x2){y0, y1};
            pz2[j] = (f32x2){z0c, z1c};
            pd2[j] = (f32x2){1e10f, 1e10f};
            sh.f.LX[i]=x0; sh.f.LY[i]=y0; sh.f.LZ[i]=z0c;
            sh.f.LX[i+1]=x1; sh.f.LY[i+1]=y1; sh.f.LZ[i+1]=z1c;
        }
        __syncthreads();
        int cur = 0;
        const int wave = t >> 6, lane = t & 63;
        f32x4 pb0, pb1, pb2, pb3;
        for (int s4 = 0; s4 < NS; s4 += 4){
            if (s4 && t == 0)
                publish_cent4(cent, b*NS + (s4 - 4), pb0, pb1, pb2, pb3);
#pragma unroll
            for (int u = 0; u < 4; ++u){
                const int s = s4 + u;
                float cx = sh.f.LX[cur], cy = sh.f.LY[cur], cz = sh.f.LZ[cur];
                if (t == 0){
                    sh.f.SC[s] = (f32x4){cx, cy, cz, 0.f};
                    f32x4 c = (f32x4){cx, cy, cz, 1.0f};
                    if (u == 0) pb0 = c; else if (u == 1) pb1 = c;
                    else if (u == 2) pb2 = c; else pb3 = c;
                }
                f32x2 ncx = (f32x2){-cx, -cx};
                f32x2 ncy = (f32x2){-cy, -cy};
                f32x2 ncz = (f32x2){-cz, -cz};
                float bestd = -1.0f; int besti = 0;
#pragma unroll
                for (int j = 0; j < FT/2; ++j){
                    f32x2 d2;
                    {
#pragma clang fp contract(off)
                        f32x2 dx = px2[j] + ncx;       // pk_add; == px - cx bit-exact
                        f32x2 dy = py2[j] + ncy;
                        f32x2 dz = pz2[j] + ncz;
                        f32x2 xx = dx*dx, yy = dy*dy, zz = dz*dz;
                        d2 = (xx + yy) + zz;
                    }
                    f32x2 nd;
                    nd.x = fminf(pd2[j].x, d2.x);
                    nd.y = fminf(pd2[j].y, d2.y);
                    pd2[j] = nd;
                    if (nd.x > bestd){ bestd = nd.x; besti = t*FT + 2*j; }
                    if (nd.y > bestd){ bestd = nd.y; besti = t*FT + 2*j + 1; }
                }
                unsigned long long key =
                    (((unsigned long long)__float_as_uint(bestd)) << 32) |
                    (unsigned long long)(~(unsigned)besti);
                DPPMAX64(key, 0x111, 0xf);   // row_shr:1
                DPPMAX64(key, 0x112, 0xf);   // row_shr:2
                DPPMAX64(key, 0x114, 0xf);   // row_shr:4
                DPPMAX64(key, 0x118, 0xf);   // row_shr:8
                DPPMAX64(key, 0x142, 0xa);   // row_bcast:15 -> rows 1,3
                DPPMAX64(key, 0x143, 0xc);   // row_bcast:31 -> rows 2,3
                int p = s & 1;
                if (lane == 63) sh.f.cand[p][wave] = key;
                __syncthreads();
                ulonglong2 c01 = *reinterpret_cast<const ulonglong2*>(&sh.f.cand[p][0]);
                ulonglong2 c23 = *reinterpret_cast<const ulonglong2*>(&sh.f.cand[p][2]);
                unsigned long long m01 = (c01.x > c01.y) ? c01.x : c01.y;
                unsigned long long m23 = (c23.x > c23.y) ? c23.x : c23.y;
                unsigned long long km  = (m01 > m23) ? m01 : m23;
                cur = (int)(~(uint32_t)km);
            }
        }
        if (t == 0)
            publish_cent4(cent, b*NS + (NS - 4), pb0, pb1, pb2, pb3);
        __syncthreads();
        for (int i = t; i < NS; i += 256){
            f32x4 c = sh.f.SC[i];
            float* o = out_newxyz + ((size_t)b*NS + i)*3;
            o[0] = c[0]; o[1] = c[1]; o[2] = c[2];
        }
    } else {
        const int w = (int)blockIdx.x - NB;
        const int stile = w >> 3;
        const int b = w & 7;
        const int wave = t >> 6, lane = t & 63;
        const int q = lane >> 4, l16 = lane & 15;

        bf16x8 Bf[4][3];
#pragma unroll
        for (int nt = 0; nt < 4; ++nt)
#pragma unroll
            for (int s = 0; s < 3; ++s)
                Bf[nt][s] = load_bf8(w0b + (nt*16 + l16)*96 + s*32 + q*8);

        if (t == 0){
            sh.w.Lc[0] = wait_cent(cent, b*NS + stile*2 + 0);
            sh.w.Lc[1] = wait_cent(cent, b*NS + stile*2 + 1);
        }
        __syncthreads();

        if (wave < 2){
            f32x4 qc = sh.w.Lc[wave];
            float qx = qc[0], qy = qc[1], qz = qc[2];
            float qn = qx*qx;
            qn = fmaf(qy, qy, qn);
            qn = fmaf(qz, qz, qn);
            const float* base = xyz + (size_t)b * (NPTS*3);
            int cnt = 0, first = 0;
            for (int c0 = 0; c0 < NPTS; c0 += 64){
                int i = c0 + lane;
                float x = base[i*3+0], y = base[i*3+1], z = base[i*3+2];
                float xn = x*x;
                xn = fmaf(y, y, xn);
                xn = fmaf(z, z, xn);
                float dot = qx*x;
                dot = fmaf(qy, y, dot);
                dot = fmaf(qz, z, dot);
                float d;
                {
#pragma clang fp contract(off)
                    d = -2.0f * dot;
                    d = d + qn;
                    d = d + xn;
                }
                bool in = !(d > R2);
                unsigned long long m = __ballot(in);
                if (in){
                    int rank = __popcll(m & ((1ull << lane) - 1ull));
                    int pos = cnt + rank;
                    if (pos < NK) sh.w.idxL[wave][pos] = i;
                }
                if (cnt == 0 && m) first = c0 + (__ffsll((unsigned long long)m) - 1);
                cnt += __popcll(m);
                if (cnt >= NK) break;
            }
            if (cnt < NK){
                for (int p = cnt + lane; p < NK; p += 64) sh.w.idxL[wave][p] = first;
            }
        }
        __syncthreads();

        const int rowbase = (b*NS + stile*2)*NK;
        const int r0 = rowbase + wave*16;
        const int cell = wave >> 1;
        const int sample = (wave & 1)*16 + l16;
        const int id = sh.w.idxL[cell][sample];
        const float* prow = pts + (((size_t)b << 12) + id)*64;
        const float* xr   = xyz + (((size_t)b << 12) + id)*3;
        f32x4 qc = sh.w.Lc[cell];
        float d0 = xr[0]-qc[0], d1 = xr[1]-qc[1], d2 = xr[2]-qc[2];

        f32x4 acc[4];
#pragma unroll
        for (int nt = 0; nt < 4; ++nt) acc[nt] = (f32x4){0.f,0.f,0.f,0.f};

#pragma unroll
        for (int s = 0; s < 3; ++s){
            const int k0 = s*32 + q*8;
            bf16x8 a;
#pragma unroll
            for (int j = 0; j < 8; ++j){
                int k = k0 + j;
                float v = (k < 3) ? ((k == 0) ? d0 : ((k == 1) ? d1 : d2))
                                  : ((k < 67) ? prow[k-3] : 0.f);
                a[j] = (short)f2bf(v);
            }
#pragma unroll
            for (int nt = 0; nt < 4; ++nt)
                acc[nt] = __builtin_amdgcn_mfma_f32_16x16x32_bf16(a, Bf[nt][s], acc[nt], 0, 0, 0);
        }
#pragma unroll
        for (int nt = 0; nt < 4; ++nt){
            int c = nt*16 + l16;
            float bb = b0[c];
            float sps = 0.f, spq = 0.f;
#pragma unroll
            for (int reg = 0; reg < 4; ++reg){
                int rr = r0 + q*4 + reg;
                float h = acc[nt][reg] + bb;
                sps += h;
                spq = fmaf(h, h, spq);
                z0[(size_t)rr*64 + c] = f2bf(h);
            }
            sh.w.S_s[wave*4 + q][c] = sps;
            sh.w.S_q[wave*4 + q][c] = spq;
        }
        __syncthreads();
        if (t < 64){
            double ss = 0.0, sq = 0.0;
#pragma unroll
            for (int i = 0; i < 16; ++i){ ss += (double)sh.w.S_s[i][t]; sq += (double)sh.w.S_q[i][t]; }
            int cp = blockIdx.x & (NCOPY-1);
            atomicAdd(&accumOut[cp*256 + t], ss);
            atomicAdd(&accumOut[cp*256 + 128 + t], sq);
        }
    }
}

// ---------------------------------------------------------------- weight prep (fp32 -> bf16) + accum zeroing + cent flag clear
__global__ void prep_kernel(const float* __restrict__ w0, const float* __restrict__ w1,
                            const float* __restrict__ w2, uint16_t* __restrict__ w0b,
                            uint16_t* __restrict__ w1b, uint16_t* __restrict__ w2b,
                            double* __restrict__ accumAll, float* __restrict__ cent){
    int t = blockIdx.x*256 + threadIdx.x;
    int stride = gridDim.x*256;
    for (int i = t; i < 3*NCOPY*256; i += stride) accumAll[i] = 0.0;
    for (int i = t; i < NB*NS; i += stride)
        ((f32x4*)cent)[i] = (f32x4){0.f, 0.f, 0.f, 0.f};
    for (int i = t; i < 64*96; i += stride){
        int n = i/96, c = i%96;
        w0b[i] = (c < 67) ? f2bf(w0[n*67 + c]) : (uint16_t)0;
    }
    for (int i = t; i < 64*64; i += stride)  w1b[i] = f2bf(w1[i]);
    for (int i = t; i < 128*64; i += stride) w2b[i] = f2bf(w2[i]);
}

// ---------------------------------------------------------------- layer 1: BN+relu+GEMM K=64 + fused stats
// r8: z1 writes staged through LDS ST[64][68] (padded stride: 34 banks ->
// q-group rows land 8 banks apart, conflict-free; copy-out b128 reads <=2-way
// = free per m136), then written as 2x coalesced 16B dwordx4/thread.
// Replaces 16x 2B scattered stores/thread (~8x transaction amplification).
// Stored BITS identical (same f2bf(h)); only the store path changed.
__global__ __launch_bounds__(256) void layer1_mfma(const uint16_t* __restrict__ zin,
                                                   const double* __restrict__ accumIn,
                                                   const float* __restrict__ g,
                                                   const float* __restrict__ be,
                                                   const uint16_t* __restrict__ wb,
                                                   const float* __restrict__ bias,
                                                   uint16_t* __restrict__ zout,
                                                   double* __restrict__ accumOut){
    constexpr int NT = 4;
    constexpr int TPB = 4;
    __shared__ float sc_l[64], sh_l[64];
    __shared__ float S_s[16][64], S_q[16][64];
    __shared__ uint16_t ST[64][68];   // staged output tile, padded (see header)
    const int t = threadIdx.x;
    if (t < 64){
        double s = 0.0, qq = 0.0;
#pragma unroll
        for (int cp = 0; cp < NCOPY; ++cp){
            s  += accumIn[cp*256 + t];
            qq += accumIn[cp*256 + 128 + t];
        }
        double mean = s / (double)NROWS;
        double var  = qq / (double)NROWS - mean*mean;
        double rs = 1.0 / sqrt(var + 1e-5);
        double scv = (double)g[t] * rs;
        sc_l[t] = (float)scv;
        sh_l[t] = (float)((double)be[t] - mean*scv);
    }
    __syncthreads();

    const int wave = t >> 6, lane = t & 63;
    const int q = lane >> 4, l16 = lane & 15;

    bf16x8 Bf[NT][2];
#pragma unroll
    for (int nt = 0; nt < NT; ++nt)
#pragma unroll
        for (int s = 0; s < 2; ++s)
            Bf[nt][s] = load_bf8(wb + (nt*16 + l16)*64 + s*32 + q*8);

    float sc[2][8], sh[2][8];
#pragma unroll
    for (int s = 0; s < 2; ++s)
#pragma unroll
        for (int j = 0; j < 8; ++j){
            sc[s][j] = sc_l[s*32 + q*8 + j];
            sh[s][j] = sh_l[s*32 + q*8 + j];
        }

    float statS[NT], statQ[NT];
#pragma unroll
    for (int nt = 0; nt < NT; ++nt){ statS[nt] = 0.f; statQ[nt] = 0.f; }
    float bb[NT];
#pragma unroll
    for (int nt = 0; nt < NT; ++nt) bb[nt] = bias[nt*16 + l16];

    // software pipeline: prime tile 0, prefetch tile+1 before computing tile
    const uint16_t* zb = zin + ((size_t)(blockIdx.x*TPB)*64 + wave*16 + l16)*64;
    uint4 cu0 = *reinterpret_cast<const uint4*>(zb + q*8);
    uint4 cu1 = *reinterpret_cast<const uint4*>(zb + 32 + q*8);

#pragma unroll
    for (int tile = 0; tile < TPB; ++tile){
        uint4 nu0 = cu0, nu1 = cu1;
        if (tile + 1 < TPB){
            const uint16_t* zn = zb + (size_t)(tile+1)*4096;   // 64 rows * 64 ch
            nu0 = *reinterpret_cast<const uint4*>(zn + q*8);
            nu1 = *reinterpret_cast<const uint4*>(zn + 32 + q*8);
        }

        f32x4 acc[NT];
#pragma unroll
        for (int nt = 0; nt < NT; ++nt) acc[nt] = (f32x4){0.f,0.f,0.f,0.f};

        uint4 uu[2] = {cu0, cu1};
#pragma unroll
        for (int s = 0; s < 2; ++s){
            uint4 u = uu[s];
            float h[8];
            h[0] = bf2f((uint16_t)(u.x & 0xFFFF)); h[1] = bf2f((uint16_t)(u.x >> 16));
            h[2] = bf2f((uint16_t)(u.y & 0xFFFF)); h[3] = bf2f((uint16_t)(u.y >> 16));
            h[4] = bf2f((uint16_t)(u.z & 0xFFFF)); h[5] = bf2f((uint16_t)(u.z >> 16));
            h[6] = bf2f((uint16_t)(u.w & 0xFFFF)); h[7] = bf2f((uint16_t)(u.w >> 16));
            bf16x8 a;
#pragma unroll
            for (int j = 0; j < 8; ++j){
                float v = fmaxf(fmaf(h[j], sc[s][j], sh[s][j]), 0.f);
                a[j] = (short)f2bf(v);
            }
#pragma unroll
            for (int nt = 0; nt < NT; ++nt)
                acc[nt] = __builtin_amdgcn_mfma_f32_16x16x32_bf16(a, Bf[nt][s], acc[nt], 0, 0, 0);
        }
        // epilogue: stats in registers, output staged to LDS
        if (tile) __syncthreads();   // prior tile's copy-out reads complete
#pragma unroll
        for (int nt = 0; nt < NT; ++nt){
            int c = nt*16 + l16;
#pragma unroll
            for (int reg = 0; reg < 4; ++reg){
                float h = acc[nt][reg] + bb[nt];
                statS[nt] += h;
                statQ[nt] = fmaf(h, h, statQ[nt]);
                ST[wave*16 + q*4 + reg][c] = f2bf(h);
            }
        }
        __syncthreads();
        // coalesced copy-out: 2 x 16B per thread, tile is 8KB contiguous
        {
            const size_t tbase = (size_t)((blockIdx.x*TPB + tile)*64);
#pragma unroll
            for (int p = 0; p < 2; ++p){
                int rowl = p*32 + (t >> 3);
                int ch   = (t & 7) * 8;
                *reinterpret_cast<uint4*>(zout + (tbase + rowl)*64 + ch) =
                    *reinterpret_cast<const uint4*>(&ST[rowl][ch]);
            }
        }
        cu0 = nu0; cu1 = nu1;
    }
    // one LDS stats exchange for the whole block
    __syncthreads();
#pragma unroll
    for (int nt = 0; nt < NT; ++nt){
        int c = nt*16 + l16;
        S_s[wave*4 + q][c] = statS[nt];
        S_q[wave*4 + q][c] = statQ[nt];
    }
    __syncthreads();
    if (t < 64){
        double ss = 0.0, sq = 0.0;
#pragma unroll
        for (int i = 0; i < 16; ++i){ ss += (double)S_s[i][t]; sq += (double)S_q[i][t]; }
        int cp = blockIdx.x & (NCOPY-1);
        atomicAdd(&accumOut[cp*256 + t], ss);
        atomicAdd(&accumOut[cp*256 + 128 + t], sq);
    }
}

// ---------------------------------------------------------------- layer 2: BN+relu+GEMM K=64 -> 128 + fused stats + pooling (UNCHANGED from r7)
__global__ __launch_bounds__(256) void layer2_mfma(const uint16_t* __restrict__ zin,
                                                   const double* __restrict__ accumIn,
                                                   const float* __restrict__ g,
                                                   const float* __restrict__ be,
                                                   const uint16_t* __restrict__ wb,
                                                   const float* __restrict__ bias,
                                                   float2* __restrict__ pool,
                                                   double* __restrict__ accumOut){
    constexpr int NT = 8;
    constexpr int TPB = 4;
    __shared__ float sc_l[64], sh_l[64];
    __shared__ float P_mx[16][128], P_mn[16][128];   // pooling; reused for stats at end
    const int t = threadIdx.x;
    if (t < 64){
        double s = 0.0, qq = 0.0;
#pragma unroll
        for (int cp = 0; cp < NCOPY; ++cp){
            s  += accumIn[cp*256 + t];
            qq += accumIn[cp*256 + 128 + t];
        }
        double mean = s / (double)NROWS;
        double var  = qq / (double)NROWS - mean*mean;
        double rs = 1.0 / sqrt(var + 1e-5);
        double scv = (double)g[t] * rs;
        sc_l[t] = (float)scv;
        sh_l[t] = (float)((double)be[t] - mean*scv);
    }
    __syncthreads();

    const int wave = t >> 6, lane = t & 63;
    const int q = lane >> 4, l16 = lane & 15;

    bf16x8 Bf[NT][2];
#pragma unroll
    for (int nt = 0; nt < NT; ++nt)
#pragma unroll
        for (int s = 0; s < 2; ++s)
            Bf[nt][s] = load_bf8(wb + (nt*16 + l16)*64 + s*32 + q*8);

    float sc[2][8], sh[2][8];
#pragma unroll
    for (int s = 0; s < 2; ++s)
#pragma unroll
        for (int j = 0; j < 8; ++j){
            sc[s][j] = sc_l[s*32 + q*8 + j];
            sh[s][j] = sh_l[s*32 + q*8 + j];
        }

    float statS[NT], statQ[NT];
#pragma unroll
    for (int nt = 0; nt < NT; ++nt){ statS[nt] = 0.f; statQ[nt] = 0.f; }
    float bb[NT];
#pragma unroll
    for (int nt = 0; nt < NT; ++nt) bb[nt] = bias[nt*16 + l16];

    const uint16_t* zb = zin + ((size_t)(blockIdx.x*TPB)*64 + wave*16 + l16)*64;
    uint4 cu0 = *reinterpret_cast<const uint4*>(zb + q*8);
    uint4 cu1 = *reinterpret_cast<const uint4*>(zb + 32 + q*8);

#pragma unroll
    for (int tile = 0; tile < TPB; ++tile){
        uint4 nu0 = cu0, nu1 = cu1;
        if (tile + 1 < TPB){
            const uint16_t* zn = zb + (size_t)(tile+1)*4096;
            nu0 = *reinterpret_cast<const uint4*>(zn + q*8);
            nu1 = *reinterpret_cast<const uint4*>(zn + 32 + q*8);
        }

        f32x4 acc[NT];
#pragma unroll
        for (int nt = 0; nt < NT; ++nt) acc[nt] = (f32x4){0.f,0.f,0.f,0.f};

        uint4 uu[2] = {cu0, cu1};
#pragma unroll
        for (int s = 0; s < 2; ++s){
            uint4 u = uu[s];
            float h[8];
            h[0] = bf2f((uint16_t)(u.x & 0xFFFF)); h[1] = bf2f((uint16_t)(u.x >> 16));
            h[2] = bf2f((uint16_t)(u.y & 0xFFFF)); h[3] = bf2f((uint16_t)(u.y >> 16));
            h[4] = bf2f((uint16_t)(u.z & 0xFFFF)); h[5] = bf2f((uint16_t)(u.z >> 16));
            h[6] = bf2f((uint16_t)(u.w & 0xFFFF)); h[7] = bf2f((uint16_t)(u.w >> 16));
            bf16x8 a;
#pragma unroll
            for (int j = 0; j < 8; ++j){
                float v = fmaxf(fmaf(h[j], sc[s][j], sh[s][j]), 0.f);
                a[j] = (short)f2bf(v);
            }
#pragma unroll
            for (int nt = 0; nt < NT; ++nt)
                acc[nt] = __builtin_amdgcn_mfma_f32_16x16x32_bf16(a, Bf[nt][s], acc[nt], 0, 0, 0);
        }
#pragma unroll
        for (int nt = 0; nt < NT; ++nt){
            int c = nt*16 + l16;
            float mx = -1e30f, mn = 1e30f;
#pragma unroll
            for (int reg = 0; reg < 4; ++reg){
                float h = acc[nt][reg] + bb[nt];
                statS[nt] += h;
                statQ[nt] = fmaf(h, h, statQ[nt]);
                mx = fmaxf(mx, h);
                mn = fminf(mn, h);
            }
            P_mx[wave*4 + q][c] = mx;
            P_mn[wave*4 + q][c] = mn;
        }
        __syncthreads();
        {
            int gidx = t >> 7;          // 0..1
            int c = t & 127;
            float mx = -1e30f, mn = 1e30f;
#pragma unroll
            for (int i = 0; i < 8; ++i){
                mx = fmaxf(mx, P_mx[gidx*8 + i][c]);
                mn = fminf(mn, P_mn[gidx*8 + i][c]);
            }
            pool[(size_t)((blockIdx.x*TPB + tile)*2 + gidx)*128 + c] = make_float2(mx, mn);
        }
        __syncthreads();
        cu0 = nu0; cu1 = nu1;
    }
    // stats exchange, reusing pooling LDS (safe: last pooling read barriered above)
#pragma unroll
    for (int nt = 0; nt < NT; ++nt){
        int c = nt*16 + l16;
        P_mx[wave*4 + q][c] = statS[nt];
        P_mn[wave*4 + q][c] = statQ[nt];
    }
    __syncthreads();
    if (t < 128){
        double ss = 0.0, sq = 0.0;
#pragma unroll
        for (int i = 0; i < 16; ++i){ ss += (double)P_mx[i][t]; sq += (double)P_mn[i][t]; }
        int cp = blockIdx.x & (NCOPY-1);
        atomicAdd(&accumOut[cp*256 + t], ss);
        atomicAdd(&accumOut[cp*256 + 128 + t], sq);
    }
}

// ---------------------------------------------------------------- final: BN-param + select + relu + COALESCED transpose via LDS (UNCHANGED from r7)
__global__ __launch_bounds__(256) void final_kernel(const float2* __restrict__ pool,
                                                    const double* __restrict__ accumIn,
                                                    const float* __restrict__ g,
                                                    const float* __restrict__ be,
                                                    float* __restrict__ out){
    __shared__ float sc_l[128], sh_l[128];
    __shared__ float Y[128][33];
    const int t = threadIdx.x;
    if (t < 128){
        double s = 0.0, qq = 0.0;
#pragma unroll
        for (int cp = 0; cp < NCOPY; ++cp){
            s  += accumIn[cp*256 + t];
            qq += accumIn[cp*256 + 128 + t];
        }
        double mean = s / (double)NROWS;
        double var  = qq / (double)NROWS - mean*mean;
        double rs = 1.0 / sqrt(var + 1e-5);
        double scv = (double)g[t] * rs;
        sc_l[t] = (float)scv;
        sh_l[t] = (float)((double)be[t] - mean*scv);
    }
    __syncthreads();

    const int b  = blockIdx.x >> 5;          // 0..7
    const int s0 = (blockIdx.x & 31) * 32;   // s slice base
    const int o  = t & 127;
    const int shalf = t >> 7;                // 0..1
    const float scv = sc_l[o], shv = sh_l[o];
#pragma unroll
    for (int it = 0; it < 16; ++it){
        int sl = it*2 + shalf;
        float2 p = pool[((size_t)(b*NS + s0 + sl))*128 + o];
        float zsel = (scv >= 0.f) ? p.x : p.y;
        Y[o][sl] = fmaxf(fmaf(zsel, scv, shv), 0.f);
    }
    __syncthreads();
#pragma unroll
    for (int pass = 0; pass < 16; ++pass){
        int oo = pass*8 + (t >> 5);
        int sl = t & 31;
        out[24576 + ((size_t)b << 17) + ((size_t)oo << 10) + s0 + sl] = Y[oo][sl];
    }
}

// ---------------------------------------------------------------- launch
extern "C" void kernel_launch(void* const* d_in, const int* in_sizes, int n_in,
                              void* d_out, int out_size, void* d_ws, size_t ws_size,
                              hipStream_t stream) {
    const float* xyz = (const float*)d_in[0];
    const float* pts = (const float*)d_in[1];
    const float* w0  = (const float*)d_in[2];
    const float* b0  = (const float*)d_in[3];
    const float* g0  = (const float*)d_in[4];
    const float* be0 = (const float*)d_in[5];
    const float* w1  = (const float*)d_in[6];
    const float* b1  = (const float*)d_in[7];
    const float* g1  = (const float*)d_in[8];
    const float* be1 = (const float*)d_in[9];
    const float* w2  = (const float*)d_in[10];
    const float* b2  = (const float*)d_in[11];
    const float* g2  = (const float*)d_in[12];
    const float* be2 = (const float*)d_in[13];
    float* out = (float*)d_out;

    char* ws = (char*)d_ws;
    double*   accum0 = (double*)(ws + 0);
    double*   accum1 = (double*)(ws + 65536);
    double*   accum2 = (double*)(ws + 131072);
    uint16_t* w0b    = (uint16_t*)(ws + 196608);    // 12288 B
    uint16_t* w1b    = (uint16_t*)(ws + 208896);    // 8192 B
    uint16_t* w2b    = (uint16_t*)(ws + 217088);    // 16384 B
    uint16_t* z0     = (uint16_t*)(ws + 262144);    // 33554432 B
    uint16_t* z1     = (uint16_t*)(ws + 33816576);  // 33554432 B
    float2*   pool   = (float2*)  (ws + 67371008);  // 8388608 B
    float*    cent   = (float*)   (ws + 75759616);  // 131072 B centroid mailboxes

    prep_kernel<<<128, 256, 0, stream>>>(w0, w1, w2, w0b, w1b, w2b, accum0, cent);
    mega_kernel<<<NB + 4096, 256, 0, stream>>>(xyz, pts, w0b, b0, z0, accum0, cent, out);
    layer1_mfma<<<1024, 256, 0, stream>>>(z0, accum0, g0, be0, w1b, b1, z1, accum1);
    layer2_mfma<<<1024, 256, 0, stream>>>(z1, accum1, g1, be1, w2b, b2, pool, accum2);
    final_kernel<<<256, 256, 0, stream>>>(pool, accum2, g2, be2, out);
}